// Round 4
// baseline (797.217 us; speedup 1.0000x reference)
//
#include <hip/hip_runtime.h>
#include <math.h>

#define PI_F 3.14159265358979323846f

namespace {
constexpr int B_ = 8;
constexpr int L_ = 3072;
constexpr int S_ = 3072;
constexpr int H_ = 8;
constexpr int NF = 544;          // fused projection width: 512 (main) + 16 (omega) + 16 (theta)
constexpr int NSC = 8;           // s-chunks for layer-0 attention
constexpr int SCHUNK = S_ / NSC; // 384
}

typedef __attribute__((ext_vector_type(8))) short bf16x8;
typedef __attribute__((ext_vector_type(4))) float f32x4;

__device__ inline f32x4 mfma16(bf16x8 a, bf16x8 b, f32x4 c) {
  return __builtin_amdgcn_mfma_f32_16x16x32_bf16(a, b, c, 0, 0, 0);
}

__device__ inline ushort f2bf(float f) {
  union { float f; unsigned u; } v;
  v.f = f;
  unsigned r = v.u + 0x7FFFu + ((v.u >> 16) & 1u);
  return (ushort)(r >> 16);
}

// async global->LDS, 16B per lane; lds base must be wave-uniform.
__device__ inline void gl_lds16(const void* g, void* l) {
  __builtin_amdgcn_global_load_lds(
      (const __attribute__((address_space(1))) unsigned int*)g,
      (__attribute__((address_space(3))) unsigned int*)l, 16, 0, 0);
}

// Bijective XCD-chunked remap (T1, m204): consecutive new-ids land on one XCD.
__device__ inline int xcd_swizzle(int flat, int nwg) {
  int q = nwg >> 3, r = nwg & 7;
  int xcd = flat & 7, ix = flat >> 3;
  return (xcd < r ? xcd * (q + 1) : r * (q + 1) + (xcd - r) * q) + ix;
}

// ---------------------------------------------------------------------------
// misc small kernels
// ---------------------------------------------------------------------------
__global__ void init_pen(float* pen) {
  if (threadIdx.x < 16) pen[threadIdx.x] = 0.f;
}

__global__ void write_pen(const float* __restrict__ pen, float* __restrict__ out) {
  if (threadIdx.x == 0) out[12582912] = pen[0];
  if (threadIdx.x == 1) out[12582913] = pen[1];
}

// Pack Wmain[512,512] | Wom[512,16] | Wth[512,16] -> Wcat[512,544] fp32 (+bias)
__global__ void pack_w(const float* __restrict__ Wm, const float* __restrict__ Wo_,
                       const float* __restrict__ Wt, const float* __restrict__ bm,
                       const float* __restrict__ bo_, const float* __restrict__ bt,
                       float* __restrict__ Wcat, float* __restrict__ bcat) {
  int gid = blockIdx.x * 256 + threadIdx.x;
  if (gid < 512 * 544) {
    int k = gid / 544, n = gid % 544;
    float v;
    if (n < 512) v = Wm[(size_t)k * 512 + n];
    else if (n < 528) v = Wo_[k * 16 + (n - 512)];
    else v = Wt[k * 16 + (n - 528)];
    Wcat[gid] = v;
  }
  if (gid < 544) {
    float v;
    if (gid < 512) v = bm[gid];
    else if (gid < 528) v = bo_[gid - 512];
    else v = bt[gid - 528];
    bcat[gid] = v;
  }
}

// Transposed bf16 weight pack: BT[640][512], rows 544..639 zeroed; bias[544].
__global__ void pack_wt_fused(const float* __restrict__ Wm, const float* __restrict__ Wo_,
                              const float* __restrict__ Wt, const float* __restrict__ bm,
                              const float* __restrict__ bo_, const float* __restrict__ bt,
                              ushort* __restrict__ BT, float* __restrict__ bias) {
  int gid = blockIdx.x * 256 + threadIdx.x;
  if (gid < 640 * 512) {
    int n = gid >> 9, k = gid & 511;
    float v = 0.f;
    if (n < 512) v = Wm[(size_t)k * 512 + n];
    else if (n < 528) v = Wo_[k * 16 + (n - 512)];
    else if (n < 544) v = Wt[k * 16 + (n - 528)];
    BT[gid] = f2bf(v);
  }
  if (gid < 544)
    bias[gid] = (gid < 512) ? bm[gid] : (gid < 528 ? bo_[gid - 512] : bt[gid - 528]);
}

// Transposed bf16 weight pack, plain 512x512 + bias[512].
__global__ void pack_wt_plain(const float* __restrict__ W, const float* __restrict__ b,
                              ushort* __restrict__ BT, float* __restrict__ bias) {
  int gid = blockIdx.x * 256 + threadIdx.x;
  if (gid < 512 * 512) {
    int n = gid >> 9, k = gid & 511;
    BT[gid] = f2bf(W[(size_t)k * 512 + n]);
  }
  if (gid < 512) bias[gid] = b[gid];
}

// fp32 -> bf16 cast, 8 elems/thread
__global__ __launch_bounds__(256)
void cast_bf16(const float* __restrict__ src, ushort* __restrict__ dst, int n8) {
  int gid = blockIdx.x * 256 + threadIdx.x;
  if (gid < n8) {
    float4 a = ((const float4*)src)[(size_t)gid * 2];
    float4 b = ((const float4*)src)[(size_t)gid * 2 + 1];
    ushort u[8] = {f2bf(a.x), f2bf(a.y), f2bf(a.z), f2bf(a.w),
                   f2bf(b.x), f2bf(b.y), f2bf(b.z), f2bf(b.w)};
    ((uint4*)dst)[gid] = *(uint4*)u;
  }
}

// ---------------------------------------------------------------------------
// bf16 MFMA GEMM: C[M,Nout] = act(A[M,512]bf16 @ BT[Npad,512]bf16^T + bias)
// 128x128 tile, BK=32, 4 waves (2x2), global_load_lds width-16 staging.
// M must be a multiple of 128. XCD-chunked tile remap for A-panel L2 reuse.
// obf=1: write bf16 (ushort) output instead of fp32.
// ---------------------------------------------------------------------------
__global__ __launch_bounds__(256)
void gemm_bf16_mfma(const ushort* __restrict__ A, const ushort* __restrict__ BT,
                    const float* __restrict__ bias, void* __restrict__ Cv,
                    int ldc, int Nout, int act, int obf) {
  __shared__ ushort As[128][32];
  __shared__ ushort Bs[128][32];
  const int tid = threadIdx.x;
  const int wv = tid >> 6, lane = tid & 63, quad = lane >> 4, col = lane & 15;
  const int wm = wv & 1, wn = wv >> 1;

  const int nwg = gridDim.x * gridDim.y;
  const int flat = blockIdx.y * gridDim.x + blockIdx.x;
  const int nf = xcd_swizzle(flat, nwg);
  const int bx = nf % gridDim.x, by = nf / gridDim.x;
  const int m0 = by * 128, n0 = bx * 128;

  const int srow = lane >> 2;        // 0..15 row within 16-row staging group
  const int scol = (lane & 3) * 8;   // ushort offset (16B granules)

  f32x4 acc[4][4];
#pragma unroll
  for (int i = 0; i < 4; ++i)
#pragma unroll
    for (int j = 0; j < 4; ++j) {
      f32x4 z = {0.f, 0.f, 0.f, 0.f};
      acc[i][j] = z;
    }

  const ushort* Ag = A + (size_t)(m0 + wv * 32) * 512;
  const ushort* Bg = BT + (size_t)(n0 + wv * 32) * 512;

  for (int k0 = 0; k0 < 512; k0 += 32) {
    __syncthreads();
    gl_lds16(Ag + (size_t)srow * 512 + k0 + scol, &As[wv * 32][0]);
    gl_lds16(Ag + (size_t)(srow + 16) * 512 + k0 + scol, &As[wv * 32 + 16][0]);
    gl_lds16(Bg + (size_t)srow * 512 + k0 + scol, &Bs[wv * 32][0]);
    gl_lds16(Bg + (size_t)(srow + 16) * 512 + k0 + scol, &Bs[wv * 32 + 16][0]);
    __syncthreads();
    bf16x8 av[4], bv[4];
#pragma unroll
    for (int mi = 0; mi < 4; ++mi)
      av[mi] = *(const bf16x8*)&As[wm * 64 + mi * 16 + col][quad * 8];
#pragma unroll
    for (int ni = 0; ni < 4; ++ni)
      bv[ni] = *(const bf16x8*)&Bs[wn * 64 + ni * 16 + col][quad * 8];
#pragma unroll
    for (int mi = 0; mi < 4; ++mi)
#pragma unroll
      for (int ni = 0; ni < 4; ++ni)
        acc[mi][ni] = mfma16(av[mi], bv[ni], acc[mi][ni]);
  }

  float* Cf = (float*)Cv;
  ushort* Cu = (ushort*)Cv;
#pragma unroll
  for (int mi = 0; mi < 4; ++mi) {
#pragma unroll
    for (int ni = 0; ni < 4; ++ni) {
      int n = n0 + wn * 64 + ni * 16 + col;
      if (n >= Nout) continue;
      float bs = bias[n];
#pragma unroll
      for (int r = 0; r < 4; ++r) {
        int m = m0 + wm * 64 + mi * 16 + quad * 4 + r;
        float v = acc[mi][ni][r] + bs;
        if (act && n >= 512) v = (n < 528) ? fmaxf(v, 0.f) : tanhf(v) * PI_F;
        if (obf) Cu[(size_t)m * ldc + n] = f2bf(v);
        else Cf[(size_t)m * ldc + n] = v;
      }
    }
  }
}

// ---------------------------------------------------------------------------
// Generic K=512 fp32 GEMM (kept for small-M dispatches).
// ---------------------------------------------------------------------------
__global__ __launch_bounds__(256)
void gemm_k512(const float* __restrict__ A, const float* __restrict__ W,
               const float* __restrict__ bias, float* __restrict__ C,
               int M, int N, int act) {
  __shared__ float As[16][68];
  __shared__ float Ws_[16][68];
  const int tid = threadIdx.x;
  const int tx = tid & 15, ty = tid >> 4;
  const int m0 = blockIdx.y * 64, n0 = blockIdx.x * 64;

  float acc[4][4];
#pragma unroll
  for (int i = 0; i < 4; ++i)
#pragma unroll
    for (int j = 0; j < 4; ++j) acc[i][j] = 0.f;

  const int arow = tid >> 2;
  const int acol4 = (tid & 3) * 4;
  const int wrow = tid >> 4;
  const int wcol4 = (tid & 15) * 4;

  for (int k0 = 0; k0 < 512; k0 += 16) {
    float4 av = make_float4(0.f, 0.f, 0.f, 0.f);
    int gm = m0 + arow;
    if (gm < M) av = *(const float4*)(A + (size_t)gm * 512 + k0 + acol4);
    As[acol4 + 0][arow] = av.x;
    As[acol4 + 1][arow] = av.y;
    As[acol4 + 2][arow] = av.z;
    As[acol4 + 3][arow] = av.w;
    float4 wv;
    int gn = n0 + wcol4;
    if (gn + 3 < N) {
      wv = *(const float4*)(W + (size_t)(k0 + wrow) * N + gn);
    } else {
      float tmp[4] = {0.f, 0.f, 0.f, 0.f};
      for (int u = 0; u < 4; ++u)
        if (gn + u < N) tmp[u] = W[(size_t)(k0 + wrow) * N + gn + u];
      wv = make_float4(tmp[0], tmp[1], tmp[2], tmp[3]);
    }
    *(float4*)&Ws_[wrow][wcol4] = wv;
    __syncthreads();
#pragma unroll
    for (int k = 0; k < 16; ++k) {
      float4 a4 = *(const float4*)&As[k][ty * 4];
      float4 b4 = *(const float4*)&Ws_[k][tx * 4];
      float a[4] = {a4.x, a4.y, a4.z, a4.w};
      float b[4] = {b4.x, b4.y, b4.z, b4.w};
#pragma unroll
      for (int i = 0; i < 4; ++i)
#pragma unroll
        for (int j = 0; j < 4; ++j) acc[i][j] = fmaf(a[i], b[j], acc[i][j]);
    }
    __syncthreads();
  }

#pragma unroll
  for (int i = 0; i < 4; ++i) {
    int gm = m0 + ty * 4 + i;
    if (gm >= M) continue;
#pragma unroll
    for (int j = 0; j < 4; ++j) {
      int gn = n0 + tx * 4 + j;
      if (gn >= N) continue;
      float v = acc[i][j] + bias[gn];
      if (act && gn >= 512) v = (gn < 528) ? fmaxf(v, 0.f) : tanhf(v) * PI_F;
      C[(size_t)gm * N + gn] = v;
    }
  }
}

// ---------------------------------------------------------------------------
// Build Qr0 bf16 [8h][96l][128d] from QF0 [96][544] (layer-0 q-side).
// ---------------------------------------------------------------------------
__global__ __launch_bounds__(256)
void build_qr0(const float* __restrict__ QF0, ushort* __restrict__ Qr0bf) {
  const int l = blockIdx.x;
  const float* row = QF0 + (size_t)l * NF;
  __shared__ float2 trig[8][2];
  const int tid = threadIdx.x;
  if (tid < 16) {
    int h = tid >> 1, m = tid & 1;
    float om = row[512 + h * 2 + m], th = row[528 + h * 2 + m];
    float qa = fmaf(om, (float)l / 96.f, th);
    trig[h][m] = make_float2(cosf(qa), sinf(qa));
  }
  __syncthreads();
  for (int idx = tid; idx < 1024; idx += 256) {
    int h = idx >> 7, d = idx & 127;
    int m = d >> 6, r = d & 63, c = r >> 4, e = r & 15;
    float qc = row[h * 64 + c * 16 + e];
    float qp = row[h * 64 + (c ^ 1) * 16 + e];
    float2 tg = trig[h][m];
    float sgn = (c == 0 || c == 3) ? -1.f : 1.f;
    Qr0bf[((size_t)h * 96 + l) * 128 + d] = f2bf(fmaf(qc, tg.x, sgn * qp * tg.y));
  }
}

// ---------------------------------------------------------------------------
// Build Kr0 bf16 [b*8+h][3072 s][128 d] from KF0 [24576][544] (layer-0 k-side).
// ---------------------------------------------------------------------------
__global__ __launch_bounds__(256)
void build_kr0(const float* __restrict__ KF0, ushort* __restrict__ Kr0) {
  const int rs = blockIdx.x;          // b*3072 + s
  const int b = rs / S_, s = rs - b * S_;
  const float* row = KF0 + (size_t)rs * NF;
  __shared__ float2 trig[8][2];
  const int tid = threadIdx.x;
  if (tid < 16) {
    int h = tid >> 1, m = tid & 1;
    float om = row[512 + h * 2 + m], th = row[528 + h * 2 + m];
    float ka = fmaf(om, (float)s * (1.f / (float)S_), th);
    trig[h][m] = make_float2(cosf(ka), sinf(ka));
  }
  __syncthreads();
  for (int idx = tid; idx < 512; idx += 256) {
    int h = idx >> 6, d = (idx & 63) * 2;
    int m = d >> 6, r = d & 63, c = r >> 4, e = r & 15;  // e even
    const float* rh = row + h * 64;
    float2 kc = *(const float2*)(rh + c * 16 + e);
    float2 kp = *(const float2*)(rh + (c ^ 2) * 16 + e);
    float2 tg = trig[h][m];
    float sgn = (c < 2) ? -1.f : 1.f;
    ushort2 u;
    u.x = f2bf(fmaf(kc.x, tg.x, sgn * kp.x * tg.y));
    u.y = f2bf(fmaf(kc.y, tg.x, sgn * kp.y * tg.y));
    *(ushort2*)&Kr0[(((size_t)(b * 8 + h)) * S_ + s) * 128 + d] = u;
  }
}

// ---------------------------------------------------------------------------
// Build Vt0 bf16 [b*8+h][64 d][3072 s] from V0b bf16 [24576][512].
// ---------------------------------------------------------------------------
__global__ __launch_bounds__(256)
void build_vt0(const ushort* __restrict__ V0b, ushort* __restrict__ Vt0) {
  const int st = blockIdx.x, h = blockIdx.y, b = blockIdx.z;
  const int s0 = st * 64;
  const int tid = threadIdx.x;
  __shared__ ushort T[64][68];
  for (int idx = tid; idx < 4096; idx += 256) {
    int s = idx >> 6, d = idx & 63;
    T[d][s] = V0b[((size_t)(b * S_ + s0 + s)) * 512 + h * 64 + d];
  }
  __syncthreads();
  for (int idx = tid; idx < 2048; idx += 256) {
    int d = idx >> 5, s2 = (idx & 31) * 2;
    ushort2 u = *(const ushort2*)&T[d][s2];
    *(ushort2*)&Vt0[(((size_t)(b * 8 + h)) * 64 + d) * S_ + s0 + s2] = u;
  }
}

// ---------------------------------------------------------------------------
// Build Kr1 bf16 [b*8+h][96 s][128 d] from KF1 [768][544] (layer-1 k-side).
// ---------------------------------------------------------------------------
__global__ __launch_bounds__(256)
void build_kr1(const float* __restrict__ KF1, ushort* __restrict__ Kr1b) {
  const int rs = blockIdx.x;
  const int b = rs / 96, s = rs % 96;
  const float* row = KF1 + (size_t)rs * NF;
  __shared__ float2 trig[8][2];
  const int tid = threadIdx.x;
  if (tid < 16) {
    int h = tid >> 1, m = tid & 1;
    float om = row[512 + h * 2 + m], th = row[528 + h * 2 + m];
    float ka = fmaf(om, (float)s / 96.f, th);
    trig[h][m] = make_float2(cosf(ka), sinf(ka));
  }
  __syncthreads();
  for (int idx = tid; idx < 512; idx += 256) {
    int h = idx >> 6, d = (idx & 63) * 2;
    int m = d >> 6, r = d & 63, c = r >> 4, e = r & 15;  // e even
    const float* rh = row + h * 64;
    float2 kc = *(const float2*)(rh + c * 16 + e);
    float2 kp = *(const float2*)(rh + (c ^ 2) * 16 + e);
    float2 tg = trig[h][m];
    float sgn = (c < 2) ? -1.f : 1.f;
    ushort2 u;
    u.x = f2bf(fmaf(kc.x, tg.x, sgn * kp.x * tg.y));
    u.y = f2bf(fmaf(kc.y, tg.x, sgn * kp.y * tg.y));
    *(ushort2*)&Kr1b[(((size_t)(b * 8 + h)) * 96 + s) * 128 + d] = u;
  }
}

// ---------------------------------------------------------------------------
// Build Qr1 bf16 [b*8+h][3072 l][128 d] from QF1 [24576][544] (layer-1 q-side).
// ---------------------------------------------------------------------------
__global__ __launch_bounds__(256)
void build_qr1(const float* __restrict__ QF1, ushort* __restrict__ Qr1) {
  const int rl = blockIdx.x;          // b*3072 + l
  const int b = rl / L_, l = rl - b * L_;
  const float* row = QF1 + (size_t)rl * NF;
  __shared__ float2 trig[8][2];
  const int tid = threadIdx.x;
  if (tid < 16) {
    int h = tid >> 1, m = tid & 1;
    float om = row[512 + h * 2 + m], th = row[528 + h * 2 + m];
    float qa = fmaf(om, (float)l * (1.f / (float)L_), th);
    trig[h][m] = make_float2(cosf(qa), sinf(qa));
  }
  __syncthreads();
  for (int idx = tid; idx < 512; idx += 256) {
    int h = idx >> 6, d = (idx & 63) * 2;
    int m = d >> 6, r = d & 63, c = r >> 4, e = r & 15;  // e even
    const float* rh = row + h * 64;
    float2 qc = *(const float2*)(rh + c * 16 + e);
    float2 qp = *(const float2*)(rh + (c ^ 1) * 16 + e);
    float2 tg = trig[h][m];
    float sgn = (c == 0 || c == 3) ? -1.f : 1.f;
    ushort2 u;
    u.x = f2bf(fmaf(qc.x, tg.x, sgn * qp.x * tg.y));
    u.y = f2bf(fmaf(qc.y, tg.x, sgn * qp.y * tg.y));
    *(ushort2*)&Qr1[(((size_t)(b * 8 + h)) * L_ + l) * 128 + d] = u;
  }
}

// ---------------------------------------------------------------------------
// Build Vt1 bf16 [b*8+h][64 d][96 s] from V1 fp32 [768][512].
// ---------------------------------------------------------------------------
__global__ __launch_bounds__(256)
void build_vt1(const float* __restrict__ V1, ushort* __restrict__ Vt1) {
  const int h = blockIdx.x, b = blockIdx.y;
  const int tid = threadIdx.x;
  __shared__ ushort T[64][104];
  for (int idx = tid; idx < 96 * 64; idx += 256) {
    int s = idx >> 6, d = idx & 63;
    T[d][s] = f2bf(V1[(size_t)(b * 96 + s) * 512 + h * 64 + d]);
  }
  __syncthreads();
  for (int idx = tid; idx < 64 * 12; idx += 256) {
    int d = idx / 12, c8 = (idx % 12) * 8;
    *(uint4*)&Vt1[(((size_t)(b * 8 + h)) * 64 + d) * 96 + c8] = *(const uint4*)&T[d][c8];
  }
}

// ---------------------------------------------------------------------------
// Layer-0 attention, MFMA. ALL K/V fragments preloaded into registers up
// front; sched_barrier(0) PINS the loads before compute (R3 lesson: without
// it the scheduler sinks them back to their uses -> serialized latency).
// grid (8 sc, 8 h, 8 b), 256 threads.
// ---------------------------------------------------------------------------
__global__ __launch_bounds__(256)
void attn0_mfma(const ushort* __restrict__ Kr0, const ushort* __restrict__ Vt0,
                const ushort* __restrict__ Qr0bf, float* __restrict__ accP,
                float* __restrict__ sumP) {
  const int sc = blockIdx.x, h = blockIdx.y, b = blockIdx.z;
  const int tid = threadIdx.x;
  const int wv = tid >> 6, lane = tid & 63, quad = lane >> 4, col = lane & 15;

  __shared__ __align__(16) ushort Qs[96][136];
  __shared__ __align__(16) ushort Ps[96][72];
  __shared__ float rowsum[96];

  const int s0g = sc * SCHUNK;
  const ushort* Kb = Kr0 + ((size_t)(b * 8 + h) * S_ + s0g) * 128;
  const ushort* Vb = Vt0 + ((size_t)(b * 8 + h)) * 64 * S_ + s0g;

  // Preload ALL K fragments (24 loads) and V fragments (12 loads) -- batched.
  bf16x8 bk[6][4];
#pragma unroll
  for (int t = 0; t < 6; ++t) {
    const ushort* Kt = Kb + ((size_t)(t * 64 + wv * 16 + col)) * 128;
#pragma unroll
    for (int k = 0; k < 4; ++k) bk[t][k] = *(const bf16x8*)(Kt + k * 32 + quad * 8);
  }
  bf16x8 bv[6][2];
  {
    const ushort* Vt = Vb + ((size_t)(wv * 16 + col)) * S_;
#pragma unroll
    for (int t = 0; t < 6; ++t) {
      bv[t][0] = *(const bf16x8*)(Vt + t * 64 + quad * 8);
      bv[t][1] = *(const bf16x8*)(Vt + t * 64 + 32 + quad * 8);
    }
  }
  // PIN: loads above may not be sunk below this point by the scheduler.
  __builtin_amdgcn_sched_barrier(0);

  // Stage Q tile (96x128 bf16) once; reused over all 6 t-iterations.
  const ushort* Qg = Qr0bf + (size_t)h * 96 * 128;
  for (int idx = tid; idx < 96 * 16; idx += 256) {
    int l = idx >> 4, c8 = (idx & 15) * 8;
    *(uint4*)&Qs[l][c8] = *(const uint4*)(Qg + (size_t)l * 128 + c8);
  }
  if (tid < 96) rowsum[tid] = 0.f;

  f32x4 oacc[6];
#pragma unroll
  for (int i = 0; i < 6; ++i) {
    f32x4 z = {0.f, 0.f, 0.f, 0.f};
    oacc[i] = z;
  }

  __syncthreads();  // Qs + rowsum ready

#pragma unroll
  for (int t = 0; t < 6; ++t) {
    f32x4 sacc[6];
#pragma unroll
    for (int mt = 0; mt < 6; ++mt) {
      f32x4 z = {0.f, 0.f, 0.f, 0.f};
      sacc[mt] = z;
#pragma unroll
      for (int k = 0; k < 4; ++k) {
        bf16x8 a = *(const bf16x8*)&Qs[mt * 16 + col][k * 32 + quad * 8];
        sacc[mt] = mfma16(a, bk[t][k], sacc[mt]);
      }
    }
#pragma unroll
    for (int mt = 0; mt < 6; ++mt) {
      float pr[4];
#pragma unroll
      for (int r = 0; r < 4; ++r) {
        float p = __expf(sacc[mt][r] * 0.0625f);
        pr[r] = p;
        Ps[mt * 16 + quad * 4 + r][wv * 16 + col] = f2bf(p);
      }
#pragma unroll
      for (int r = 0; r < 4; ++r) {
#pragma unroll
        for (int off = 1; off < 16; off <<= 1) pr[r] += __shfl_xor(pr[r], off);
      }
      if (col == 0) {
#pragma unroll
        for (int r = 0; r < 4; ++r)
          atomicAdd(&rowsum[mt * 16 + quad * 4 + r], pr[r]);
      }
    }
    __syncthreads();  // Ps visible to all waves
#pragma unroll
    for (int mt = 0; mt < 6; ++mt) {
      bf16x8 a0 = *(const bf16x8*)&Ps[mt * 16 + col][quad * 8];
      oacc[mt] = mfma16(a0, bv[t][0], oacc[mt]);
      bf16x8 a1 = *(const bf16x8*)&Ps[mt * 16 + col][32 + quad * 8];
      oacc[mt] = mfma16(a1, bv[t][1], oacc[mt]);
    }
    __syncthreads();  // Ps reads done before next iter overwrites
  }
  const size_t pbase = (((size_t)(b * 8 + h)) * NSC + sc) * 96;
#pragma unroll
  for (int mt = 0; mt < 6; ++mt) {
#pragma unroll
    for (int r = 0; r < 4; ++r) {
      int l = mt * 16 + quad * 4 + r;
      accP[(pbase + l) * 64 + wv * 16 + col] = oacc[mt][r];
    }
  }
  if (tid < 96) sumP[pbase + tid] = rowsum[tid];
}

// Stage 2: combine the NSC chunk partials -> attn0 [b*96+l][h*64+d]
__global__ __launch_bounds__(256)
void attn0_stage2(const float* __restrict__ accP, const float* __restrict__ sumP,
                  float* __restrict__ attn0) {
  const int l = blockIdx.x, b = blockIdx.y;
  const int tid = threadIdx.x;
  for (int e = tid; e < 512; e += 256) {
    int h = e >> 6, d = e & 63;
    size_t base = ((size_t)(b * 8 + h)) * NSC * 96;
    float num = 0.f, den = 0.f;
    for (int scv = 0; scv < NSC; ++scv) {
      size_t pb = base + (size_t)scv * 96 + l;
      num += accP[pb * 64 + d];
      den += sumP[pb];
    }
    attn0[((size_t)(b * 96 + l)) * 512 + e] = num / den;
  }
}

// ---------------------------------------------------------------------------
// trend_norm: moving_avg(k=25, edge-replicated) -> LayerNorm(seasonal) + trend
// ---------------------------------------------------------------------------
__global__ __launch_bounds__(256)
void trend_norm(const float* __restrict__ y, const float* __restrict__ g,
                const float* __restrict__ be, float* __restrict__ outp) {
  const int t = blockIdx.x, b = blockIdx.y;
  const int tid = threadIdx.x;
  __shared__ float red[256];
  __shared__ float red2[256];
  float seas[2], trend[2];
  float lsum = 0.f, lsum2 = 0.f;
#pragma unroll
  for (int u = 0; u < 2; ++u) {
    int d = tid + u * 256;
    float tr = 0.f;
    for (int j = -12; j <= 12; ++j) {
      int tt = t + j;
      tt = tt < 0 ? 0 : (tt > 95 ? 95 : tt);
      tr += y[((size_t)(b * 96 + tt)) * 512 + d];
    }
    tr *= (1.f / 25.f);
    float x = y[((size_t)(b * 96 + t)) * 512 + d];
    float se = x - tr;
    seas[u] = se;
    trend[u] = tr;
    lsum += se;
    lsum2 += se * se;
  }
  red[tid] = lsum;
  red2[tid] = lsum2;
  __syncthreads();
  for (int off = 128; off > 0; off >>= 1) {
    if (tid < off) {
      red[tid] += red[tid + off];
      red2[tid] += red2[tid + off];
    }
    __syncthreads();
  }
  float mu = red[0] / 512.f;
  float var = red2[0] / 512.f - mu * mu;
  float rs = rsqrtf(var + 1e-5f);
#pragma unroll
  for (int u = 0; u < 2; ++u) {
    int d = tid + u * 256;
    outp[((size_t)(b * 96 + t)) * 512 + d] = (seas[u] - mu) * rs * g[d] + be[d] + trend[u];
  }
}

// ---------------------------------------------------------------------------
// Penalty: sum(diff(om, axis=seq)^2) and sum(th^2) over a fused proj buffer.
// ---------------------------------------------------------------------------
__global__ __launch_bounds__(256)
void penalty(const float* __restrict__ base, int R, int nb, float mult,
             float* __restrict__ pen) {
  const int tid = threadIdx.x;
  size_t gid = (size_t)blockIdx.x * 256 + tid;
  size_t total = (size_t)nb * R * 16;
  float omv = 0.f, thv = 0.f;
  if (gid < total) {
    int j = (int)(gid & 15);
    size_t row = gid >> 4;
    int s = (int)(row % R);
    const float* r0 = base + row * NF;
    float th = r0[528 + j];
    thv = th * th;
    if (s < R - 1) {
      float d = r0[NF + 512 + j] - r0[512 + j];
      omv = d * d;
    }
  }
  __shared__ float ro[256], rt[256];
  ro[tid] = omv;
  rt[tid] = thv;
  __syncthreads();
  for (int off = 128; off > 0; off >>= 1) {
    if (tid < off) {
      ro[tid] += ro[tid + off];
      rt[tid] += rt[tid + off];
    }
    __syncthreads();
  }
  if (tid == 0) {
    atomicAdd(pen + 0, mult * ro[0]);
    atomicAdd(pen + 1, mult * rt[0]);
  }
}

// ---------------------------------------------------------------------------
// Layer-1 attention, MFMA. ALL fragments (Q,K,V = 40 x 16B loads) preloaded;
// sched_barrier(0) PINS them before the first MFMA (R3: without the pin the
// scheduler sinks the loads -> 36 serialized round-trips, VGPR stayed 56).
// grid (48 ltiles of 64, 8h, 8b). bf16 output.
// ---------------------------------------------------------------------------
__global__ __launch_bounds__(256)
void attn1_mfma(const ushort* __restrict__ Qr1, const ushort* __restrict__ Kr1b,
                const ushort* __restrict__ Vt1, ushort* __restrict__ attn1) {
  const int nwg = gridDim.x * gridDim.y * gridDim.z;
  const int flat = (blockIdx.z * gridDim.y + blockIdx.y) * gridDim.x + blockIdx.x;
  const int nf = xcd_swizzle(flat, nwg);
  const int lt = nf % gridDim.x;
  const int rest = nf / gridDim.x;
  const int h = rest % gridDim.y, b = rest / gridDim.y;
  const int l0 = lt * 64;
  const int tid = threadIdx.x;
  const int wv = tid >> 6, lane = tid & 63, quad = lane >> 4, col = lane & 15;

  __shared__ __align__(16) ushort Ps[64][104];

  const ushort* Qg = Qr1 + ((size_t)(b * 8 + h) * L_ + l0) * 128;
  const ushort* Kg = Kr1b + (size_t)(b * 8 + h) * 96 * 128;
  const ushort* Vg = Vt1 + (size_t)(b * 8 + h) * 64 * 96;

  // Preload ALL fragments: 4 Q + 24 K + 12 V = 40 batched 16B loads.
  bf16x8 aq[4];
#pragma unroll
  for (int k = 0; k < 4; ++k)
    aq[k] = *(const bf16x8*)(Qg + ((size_t)(wv * 16 + col)) * 128 + k * 32 + quad * 8);
  bf16x8 bk[6][4];
#pragma unroll
  for (int nt = 0; nt < 6; ++nt)
#pragma unroll
    for (int k = 0; k < 4; ++k)
      bk[nt][k] =
          *(const bf16x8*)(Kg + ((size_t)(nt * 16 + col)) * 128 + k * 32 + quad * 8);
  bf16x8 bv[4][3];
#pragma unroll
  for (int nt = 0; nt < 4; ++nt)
#pragma unroll
    for (int kt = 0; kt < 3; ++kt)
      bv[nt][kt] =
          *(const bf16x8*)(Vg + ((size_t)(nt * 16 + col)) * 96 + kt * 32 + quad * 8);
  // PIN: loads above may not be sunk below this point by the scheduler.
  __builtin_amdgcn_sched_barrier(0);

  f32x4 sacc[6];
#pragma unroll
  for (int nt = 0; nt < 6; ++nt) {
    f32x4 z = {0.f, 0.f, 0.f, 0.f};
    sacc[nt] = z;
#pragma unroll
    for (int k = 0; k < 4; ++k) sacc[nt] = mfma16(aq[k], bk[nt][k], sacc[nt]);
  }
  float rsum[4] = {0.f, 0.f, 0.f, 0.f};
#pragma unroll
  for (int nt = 0; nt < 6; ++nt) {
#pragma unroll
    for (int r = 0; r < 4; ++r) {
      float p = __expf(sacc[nt][r] * 0.0625f);
      Ps[wv * 16 + quad * 4 + r][nt * 16 + col] = f2bf(p);
      rsum[r] += p;
    }
  }
#pragma unroll
  for (int r = 0; r < 4; ++r) {
#pragma unroll
    for (int off = 1; off < 16; off <<= 1) rsum[r] += __shfl_xor(rsum[r], off);
  }
  __syncthreads();
  bf16x8 ap[3];
#pragma unroll
  for (int kt = 0; kt < 3; ++kt)
    ap[kt] = *(const bf16x8*)&Ps[wv * 16 + col][kt * 32 + quad * 8];
  f32x4 oacc[4];
#pragma unroll
  for (int nt = 0; nt < 4; ++nt) {
    f32x4 z = {0.f, 0.f, 0.f, 0.f};
    oacc[nt] = z;
#pragma unroll
    for (int kt = 0; kt < 3; ++kt) oacc[nt] = mfma16(ap[kt], bv[nt][kt], oacc[nt]);
  }
  float inv[4];
#pragma unroll
  for (int r = 0; r < 4; ++r) inv[r] = 1.f / rsum[r];
#pragma unroll
  for (int nt = 0; nt < 4; ++nt) {
#pragma unroll
    for (int r = 0; r < 4; ++r) {
      int l = wv * 16 + quad * 4 + r;
      attn1[(size_t)(b * L_ + l0 + l) * 512 + h * 64 + nt * 16 + col] =
          f2bf(oacc[nt][r] * inv[r]);
    }
  }
}

// ---------------------------------------------------------------------------
extern "C" void kernel_launch(void* const* d_in, const int* in_sizes, int n_in,
                              void* d_out, int out_size, void* d_ws, size_t ws_size,
                              hipStream_t stream) {
  (void)in_sizes; (void)n_in; (void)out_size; (void)ws_size;
  const float* queries = (const float*)d_in[0];
  const float* keys = (const float*)d_in[1];
  const float* values = (const float*)d_in[2];
  const float* Wq = (const float*)d_in[3];
  const float* bq = (const float*)d_in[4];
  const float* Wk = (const float*)d_in[5];
  const float* bk = (const float*)d_in[6];
  const float* Wv = (const float*)d_in[7];
  const float* bv = (const float*)d_in[8];
  const float* Wqo = (const float*)d_in[9];
  const float* bqo = (const float*)d_in[10];
  const float* Wko = (const float*)d_in[11];
  const float* bko = (const float*)d_in[12];
  const float* Wqt = (const float*)d_in[13];
  const float* bqt = (const float*)d_in[14];
  const float* Wkt = (const float*)d_in[15];
  const float* bkt = (const float*)d_in[16];
  const float* Wo = (const float*)d_in[17];
  const float* bo = (const float*)d_in[18];
  const float* I = (const float*)d_in[19];
  const float* ln_g = (const float*)d_in[20];
  const float* ln_b = (const float*)d_in[21];
  float* out = (float*)d_out;

  float* ws = (float*)d_ws;
  size_t off = 0;
  auto alloc = [&](size_t n) {
    float* p = ws + off;
    off += (n + 3) & ~(size_t)3;
    return p;
  };
  auto allocU = [&](size_t n) { return (ushort*)alloc((n + 1) / 2); };

  // fp32 packed weights (small-M gemms)
  float* WCAT0Q = alloc(512 * 544);
  float* WCAT1K = alloc(512 * 544);
  float* BCAT0Q = alloc(544);
  float* BCAT1K = alloc(544);
  // bf16 transposed weights (big gemms)
  ushort* BT0K = allocU(640 * 512);
  ushort* BT1Q = allocU(640 * 512);
  ushort* BTV0 = allocU(512 * 512);
  ushort* BTO1 = allocU(512 * 512);
  float* B0K = alloc(544);
  float* B1Q = alloc(544);
  float* BV0 = alloc(512);
  float* BO1 = alloc(512);
  float* pen = alloc(16);
  float* QF0 = alloc(96 * 544);
  ushort* Qr0bf = allocU(8 * 96 * 128);
  float* KF0 = alloc((size_t)24576 * 544);  // reused as QF1
  float* V0 = alloc((size_t)24576 * 512);   // bf16 V0 in first half; reused as Qr1
  float* attn0 = alloc(768 * 512);
  float* y0 = alloc(768 * 512);
  float* xind = alloc(768 * 512);
  float* KF1 = alloc(768 * 544);
  float* V1 = alloc(768 * 512);
  ushort* Kr1b = allocU((size_t)64 * 96 * 128);  // bf16 rotated K, layer 1
  ushort* Vt1 = allocU((size_t)64 * 64 * 96);    // bf16 transposed V, layer 1
  float* accP = alloc((size_t)64 * NSC * 96 * 64);
  float* sumP = alloc((size_t)64 * NSC * 96);
  // XB1/XB2 MUST stay adjacent: their union (2 x 12,582,912 ushorts) is
  // reused as Kr0 bf16 [64][3072][128] = 25,165,824 ushorts during attn0.
  ushort* XB1 = allocU((size_t)24576 * 512);  // keysB, then Kr0 lo, then queriesB
  ushort* XB2 = allocU((size_t)24576 * 512);  // valuesB, then Kr0 hi, then attn1 out
  ushort* Kr0U = XB1;
  ushort* Vt0U = allocU((size_t)64 * 64 * S_);  // 25.2 MB
  float* QF1 = KF0;
  ushort* V0b = (ushort*)V0;   // bf16 V0 [24576][512] (25 MB in the 50 MB region)
  ushort* Qr1U = (ushort*)V0;  // later: Qr1 bf16 (V0b dead after build_vt0)

  init_pen<<<1, 64, 0, stream>>>(pen);
  const int packBlocks = (512 * 544 + 255) / 256;
  pack_w<<<packBlocks, 256, 0, stream>>>(Wq, Wqo, Wqt, bq, bqo, bqt, WCAT0Q, BCAT0Q);
  pack_w<<<packBlocks, 256, 0, stream>>>(Wk + 262144, Wko + 8192, Wkt + 8192,
                                         bk + 512, bko + 16, bkt + 16, WCAT1K, BCAT1K);
  pack_wt_fused<<<(640 * 512 + 255) / 256, 256, 0, stream>>>(
      Wk, Wko, Wkt, bk, bko, bkt, BT0K, B0K);
  pack_wt_fused<<<(640 * 512 + 255) / 256, 256, 0, stream>>>(
      Wq + 262144, Wqo + 8192, Wqt + 8192, bq + 512, bqo + 16, bqt + 16, BT1Q, B1Q);
  pack_wt_plain<<<(512 * 512 + 255) / 256, 256, 0, stream>>>(Wv, bv, BTV0, BV0);
  pack_wt_plain<<<(512 * 512 + 255) / 256, 256, 0, stream>>>(Wo + 262144, bo + 512,
                                                             BTO1, BO1);
  const int castBlocks = (24576 * 512 / 8 + 255) / 256;
  cast_bf16<<<castBlocks, 256, 0, stream>>>(keys, XB1, 24576 * 512 / 8);
  cast_bf16<<<castBlocks, 256, 0, stream>>>(values, XB2, 24576 * 512 / 8);

  // ---- layer 0 ----
  gemm_bf16_mfma<<<dim3(5, 192), 256, 0, stream>>>(XB1, BT0K, B0K, KF0, 544, 544, 1, 0);
  gemm_bf16_mfma<<<dim3(4, 192), 256, 0, stream>>>(XB2, BTV0, BV0, V0b, 512, 512, 0, 1);
  gemm_k512<<<dim3(9, 2), 256, 0, stream>>>(I, WCAT0Q, BCAT0Q, QF0, 96, 544, 1);
  build_qr0<<<96, 256, 0, stream>>>(QF0, Qr0bf);
  penalty<<<(96 * 16 + 255) / 256, 256, 0, stream>>>(QF0, 96, 1, 8.f, pen);
  penalty<<<(24576 * 16 + 255) / 256, 256, 0, stream>>>(KF0, 3072, 8, 1.f, pen);
  build_kr0<<<24576, 256, 0, stream>>>(KF0, Kr0U);        // overwrites XB1+XB2
  build_vt0<<<dim3(48, 8, 8), 256, 0, stream>>>(V0b, Vt0U);
  attn0_mfma<<<dim3(8, 8, 8), 256, 0, stream>>>(Kr0U, Vt0U, Qr0bf, accP, sumP);
  attn0_stage2<<<dim3(96, 8), 256, 0, stream>>>(accP, sumP, attn0);
  gemm_k512<<<dim3(8, 12), 256, 0, stream>>>(attn0, Wo, bo, y0, 768, 512, 0);
  trend_norm<<<dim3(96, 8), 256, 0, stream>>>(y0, ln_g, ln_b, xind);

  // ---- layer 1 ----
  gemm_k512<<<dim3(9, 12), 256, 0, stream>>>(xind, WCAT1K, BCAT1K, KF1, 768, 544, 1);
  gemm_k512<<<dim3(8, 12), 256, 0, stream>>>(xind, Wv + 262144, bv + 512, V1, 768, 512, 0);
  build_kr1<<<768, 256, 0, stream>>>(KF1, Kr1b);
  build_vt1<<<dim3(8, 8), 256, 0, stream>>>(V1, Vt1);
  penalty<<<(768 * 16 + 255) / 256, 256, 0, stream>>>(KF1, 96, 8, 1.f, pen);
  cast_bf16<<<castBlocks, 256, 0, stream>>>(queries, XB1, 24576 * 512 / 8);
  gemm_bf16_mfma<<<dim3(5, 192), 256, 0, stream>>>(XB1, BT1Q, B1Q, QF1, 544, 544, 1, 0);
  penalty<<<(24576 * 16 + 255) / 256, 256, 0, stream>>>(QF1, 3072, 8, 1.f, pen);
  build_qr1<<<24576, 256, 0, stream>>>(QF1, Qr1U);        // overwrites V0b
  attn1_mfma<<<dim3(48, 8, 8), 256, 0, stream>>>(Qr1U, Kr1b, Vt1, XB2);
  gemm_bf16_mfma<<<dim3(4, 192), 256, 0, stream>>>(XB2, BTO1, BO1, out, 512, 512, 0, 0);
  write_pen<<<1, 64, 0, stream>>>(pen, out);
}

// Round 5
// 794.714 us; speedup vs baseline: 1.0032x; 1.0032x over previous
//
#include <hip/hip_runtime.h>
#include <math.h>

#define PI_F 3.14159265358979323846f

namespace {
constexpr int B_ = 8;
constexpr int L_ = 3072;
constexpr int S_ = 3072;
constexpr int H_ = 8;
constexpr int NF = 544;          // fused projection width: 512 (main) + 16 (omega) + 16 (theta)
constexpr int NSC = 8;           // s-chunks for layer-0 attention
constexpr int SCHUNK = S_ / NSC; // 384
}

typedef __attribute__((ext_vector_type(8))) short bf16x8;
typedef __attribute__((ext_vector_type(4))) float f32x4;

__device__ inline f32x4 mfma16(bf16x8 a, bf16x8 b, f32x4 c) {
  return __builtin_amdgcn_mfma_f32_16x16x32_bf16(a, b, c, 0, 0, 0);
}

__device__ inline ushort f2bf(float f) {
  union { float f; unsigned u; } v;
  v.f = f;
  unsigned r = v.u + 0x7FFFu + ((v.u >> 16) & 1u);
  return (ushort)(r >> 16);
}

// async global->LDS, 16B per lane; lds base must be wave-uniform.
__device__ inline void gl_lds16(const void* g, void* l) {
  __builtin_amdgcn_global_load_lds(
      (const __attribute__((address_space(1))) unsigned int*)g,
      (__attribute__((address_space(3))) unsigned int*)l, 16, 0, 0);
}

// Bijective XCD-chunked remap (T1, m204): consecutive new-ids land on one XCD.
__device__ inline int xcd_swizzle(int flat, int nwg) {
  int q = nwg >> 3, r = nwg & 7;
  int xcd = flat & 7, ix = flat >> 3;
  return (xcd < r ? xcd * (q + 1) : r * (q + 1) + (xcd - r) * q) + ix;
}

// ---------------------------------------------------------------------------
// misc small kernels
// ---------------------------------------------------------------------------
__global__ void init_pen(float* pen) {
  if (threadIdx.x < 16) pen[threadIdx.x] = 0.f;
}

__global__ void write_pen(const float* __restrict__ pen, float* __restrict__ out) {
  if (threadIdx.x == 0) out[12582912] = pen[0];
  if (threadIdx.x == 1) out[12582913] = pen[1];
}

// Pack Wmain[512,512] | Wom[512,16] | Wth[512,16] -> Wcat[512,544] fp32 (+bias)
__global__ void pack_w(const float* __restrict__ Wm, const float* __restrict__ Wo_,
                       const float* __restrict__ Wt, const float* __restrict__ bm,
                       const float* __restrict__ bo_, const float* __restrict__ bt,
                       float* __restrict__ Wcat, float* __restrict__ bcat) {
  int gid = blockIdx.x * 256 + threadIdx.x;
  if (gid < 512 * 544) {
    int k = gid / 544, n = gid % 544;
    float v;
    if (n < 512) v = Wm[(size_t)k * 512 + n];
    else if (n < 528) v = Wo_[k * 16 + (n - 512)];
    else v = Wt[k * 16 + (n - 528)];
    Wcat[gid] = v;
  }
  if (gid < 544) {
    float v;
    if (gid < 512) v = bm[gid];
    else if (gid < 528) v = bo_[gid - 512];
    else v = bt[gid - 528];
    bcat[gid] = v;
  }
}

// Transposed bf16 weight pack: BT[640][512], rows 544..639 zeroed; bias[544].
__global__ void pack_wt_fused(const float* __restrict__ Wm, const float* __restrict__ Wo_,
                              const float* __restrict__ Wt, const float* __restrict__ bm,
                              const float* __restrict__ bo_, const float* __restrict__ bt,
                              ushort* __restrict__ BT, float* __restrict__ bias) {
  int gid = blockIdx.x * 256 + threadIdx.x;
  if (gid < 640 * 512) {
    int n = gid >> 9, k = gid & 511;
    float v = 0.f;
    if (n < 512) v = Wm[(size_t)k * 512 + n];
    else if (n < 528) v = Wo_[k * 16 + (n - 512)];
    else if (n < 544) v = Wt[k * 16 + (n - 528)];
    BT[gid] = f2bf(v);
  }
  if (gid < 544)
    bias[gid] = (gid < 512) ? bm[gid] : (gid < 528 ? bo_[gid - 512] : bt[gid - 528]);
}

// Transposed bf16 weight pack, plain 512x512 + bias[512].
__global__ void pack_wt_plain(const float* __restrict__ W, const float* __restrict__ b,
                              ushort* __restrict__ BT, float* __restrict__ bias) {
  int gid = blockIdx.x * 256 + threadIdx.x;
  if (gid < 512 * 512) {
    int n = gid >> 9, k = gid & 511;
    BT[gid] = f2bf(W[(size_t)k * 512 + n]);
  }
  if (gid < 512) bias[gid] = b[gid];
}

// fp32 -> bf16 cast, 8 elems/thread
__global__ __launch_bounds__(256)
void cast_bf16(const float* __restrict__ src, ushort* __restrict__ dst, int n8) {
  int gid = blockIdx.x * 256 + threadIdx.x;
  if (gid < n8) {
    float4 a = ((const float4*)src)[(size_t)gid * 2];
    float4 b = ((const float4*)src)[(size_t)gid * 2 + 1];
    ushort u[8] = {f2bf(a.x), f2bf(a.y), f2bf(a.z), f2bf(a.w),
                   f2bf(b.x), f2bf(b.y), f2bf(b.z), f2bf(b.w)};
    ((uint4*)dst)[gid] = *(uint4*)u;
  }
}

// ---------------------------------------------------------------------------
// bf16 MFMA GEMM: C[M,Nout] = act(A[M,512]bf16 @ BT[Npad,512]bf16^T + bias)
// 128x128 tile, BK=32, 4 waves (2x2), DOUBLE-BUFFERED global_load_lds with
// 2-phase prefetch (catalog T3-minimum): issue next tile's loads BEFORE
// computing current tile; one vmcnt(0)+raw-barrier per K-step (loads get a
// full MFMA section in flight instead of a serialized drain).
// M multiple of 128. XCD-chunked tile remap. obf=1 -> bf16 output.
// ---------------------------------------------------------------------------
__global__ __launch_bounds__(256)
void gemm_bf16_mfma(const ushort* __restrict__ A, const ushort* __restrict__ BT,
                    const float* __restrict__ bias, void* __restrict__ Cv,
                    int ldc, int Nout, int act, int obf) {
  __shared__ ushort As[2][128][32];
  __shared__ ushort Bs[2][128][32];
  const int tid = threadIdx.x;
  const int wv = tid >> 6, lane = tid & 63, quad = lane >> 4, col = lane & 15;
  const int wm = wv & 1, wn = wv >> 1;

  const int nwg = gridDim.x * gridDim.y;
  const int flat = blockIdx.y * gridDim.x + blockIdx.x;
  const int nf = xcd_swizzle(flat, nwg);
  const int bx = nf % gridDim.x, by = nf / gridDim.x;
  const int m0 = by * 128, n0 = bx * 128;

  const int srow = lane >> 2;        // 0..15 row within 16-row staging group
  const int scol = (lane & 3) * 8;   // ushort offset (16B granules)

  f32x4 acc[4][4];
#pragma unroll
  for (int i = 0; i < 4; ++i)
#pragma unroll
    for (int j = 0; j < 4; ++j) {
      f32x4 z = {0.f, 0.f, 0.f, 0.f};
      acc[i][j] = z;
    }

  const ushort* Ag = A + (size_t)(m0 + wv * 32) * 512;
  const ushort* Bg = BT + (size_t)(n0 + wv * 32) * 512;

  auto stage = [&](int bb, int k0) {
    gl_lds16(Ag + (size_t)srow * 512 + k0 + scol, &As[bb][wv * 32][0]);
    gl_lds16(Ag + (size_t)(srow + 16) * 512 + k0 + scol, &As[bb][wv * 32 + 16][0]);
    gl_lds16(Bg + (size_t)srow * 512 + k0 + scol, &Bs[bb][wv * 32][0]);
    gl_lds16(Bg + (size_t)(srow + 16) * 512 + k0 + scol, &Bs[bb][wv * 32 + 16][0]);
  };

  // prologue: fill buffer 0
  stage(0, 0);
  asm volatile("s_waitcnt vmcnt(0)" ::: "memory");
  __builtin_amdgcn_s_barrier();
  __builtin_amdgcn_sched_barrier(0);

  for (int i = 0; i < 16; ++i) {
    const int cur = i & 1;
    if (i < 15) stage(cur ^ 1, (i + 1) * 32);  // prefetch next K-tile
    bf16x8 av[4], bv[4];
#pragma unroll
    for (int mi = 0; mi < 4; ++mi)
      av[mi] = *(const bf16x8*)&As[cur][wm * 64 + mi * 16 + col][quad * 8];
#pragma unroll
    for (int ni = 0; ni < 4; ++ni)
      bv[ni] = *(const bf16x8*)&Bs[cur][wn * 64 + ni * 16 + col][quad * 8];
#pragma unroll
    for (int mi = 0; mi < 4; ++mi)
#pragma unroll
      for (int ni = 0; ni < 4; ++ni)
        acc[mi][ni] = mfma16(av[mi], bv[ni], acc[mi][ni]);
    // Pin MFMAs + their LDS waits above the barrier (rule #18), then wait the
    // prefetch (had a full MFMA section in flight) and sync buffer swap.
    __builtin_amdgcn_sched_barrier(0);
    asm volatile("s_waitcnt vmcnt(0)" ::: "memory");
    __builtin_amdgcn_s_barrier();
    __builtin_amdgcn_sched_barrier(0);
  }

  float* Cf = (float*)Cv;
  ushort* Cu = (ushort*)Cv;
#pragma unroll
  for (int mi = 0; mi < 4; ++mi) {
#pragma unroll
    for (int ni = 0; ni < 4; ++ni) {
      int n = n0 + wn * 64 + ni * 16 + col;
      if (n >= Nout) continue;
      float bs = bias[n];
#pragma unroll
      for (int r = 0; r < 4; ++r) {
        int m = m0 + wm * 64 + mi * 16 + quad * 4 + r;
        float v = acc[mi][ni][r] + bs;
        if (act && n >= 512) v = (n < 528) ? fmaxf(v, 0.f) : tanhf(v) * PI_F;
        if (obf) Cu[(size_t)m * ldc + n] = f2bf(v);
        else Cf[(size_t)m * ldc + n] = v;
      }
    }
  }
}

// ---------------------------------------------------------------------------
// Generic K=512 fp32 GEMM (kept for small-M dispatches).
// ---------------------------------------------------------------------------
__global__ __launch_bounds__(256)
void gemm_k512(const float* __restrict__ A, const float* __restrict__ W,
               const float* __restrict__ bias, float* __restrict__ C,
               int M, int N, int act) {
  __shared__ float As[16][68];
  __shared__ float Ws_[16][68];
  const int tid = threadIdx.x;
  const int tx = tid & 15, ty = tid >> 4;
  const int m0 = blockIdx.y * 64, n0 = blockIdx.x * 64;

  float acc[4][4];
#pragma unroll
  for (int i = 0; i < 4; ++i)
#pragma unroll
    for (int j = 0; j < 4; ++j) acc[i][j] = 0.f;

  const int arow = tid >> 2;
  const int acol4 = (tid & 3) * 4;
  const int wrow = tid >> 4;
  const int wcol4 = (tid & 15) * 4;

  for (int k0 = 0; k0 < 512; k0 += 16) {
    float4 av = make_float4(0.f, 0.f, 0.f, 0.f);
    int gm = m0 + arow;
    if (gm < M) av = *(const float4*)(A + (size_t)gm * 512 + k0 + acol4);
    As[acol4 + 0][arow] = av.x;
    As[acol4 + 1][arow] = av.y;
    As[acol4 + 2][arow] = av.z;
    As[acol4 + 3][arow] = av.w;
    float4 wv;
    int gn = n0 + wcol4;
    if (gn + 3 < N) {
      wv = *(const float4*)(W + (size_t)(k0 + wrow) * N + gn);
    } else {
      float tmp[4] = {0.f, 0.f, 0.f, 0.f};
      for (int u = 0; u < 4; ++u)
        if (gn + u < N) tmp[u] = W[(size_t)(k0 + wrow) * N + gn + u];
      wv = make_float4(tmp[0], tmp[1], tmp[2], tmp[3]);
    }
    *(float4*)&Ws_[wrow][wcol4] = wv;
    __syncthreads();
#pragma unroll
    for (int k = 0; k < 16; ++k) {
      float4 a4 = *(const float4*)&As[k][ty * 4];
      float4 b4 = *(const float4*)&Ws_[k][tx * 4];
      float a[4] = {a4.x, a4.y, a4.z, a4.w};
      float b[4] = {b4.x, b4.y, b4.z, b4.w};
#pragma unroll
      for (int i = 0; i < 4; ++i)
#pragma unroll
        for (int j = 0; j < 4; ++j) acc[i][j] = fmaf(a[i], b[j], acc[i][j]);
    }
    __syncthreads();
  }

#pragma unroll
  for (int i = 0; i < 4; ++i) {
    int gm = m0 + ty * 4 + i;
    if (gm >= M) continue;
#pragma unroll
    for (int j = 0; j < 4; ++j) {
      int gn = n0 + tx * 4 + j;
      if (gn >= N) continue;
      float v = acc[i][j] + bias[gn];
      if (act && gn >= 512) v = (gn < 528) ? fmaxf(v, 0.f) : tanhf(v) * PI_F;
      C[(size_t)gm * N + gn] = v;
    }
  }
}

// ---------------------------------------------------------------------------
// Build Qr0 bf16 [8h][96l][128d] from QF0 [96][544] (layer-0 q-side).
// ---------------------------------------------------------------------------
__global__ __launch_bounds__(256)
void build_qr0(const float* __restrict__ QF0, ushort* __restrict__ Qr0bf) {
  const int l = blockIdx.x;
  const float* row = QF0 + (size_t)l * NF;
  __shared__ float2 trig[8][2];
  const int tid = threadIdx.x;
  if (tid < 16) {
    int h = tid >> 1, m = tid & 1;
    float om = row[512 + h * 2 + m], th = row[528 + h * 2 + m];
    float qa = fmaf(om, (float)l / 96.f, th);
    trig[h][m] = make_float2(cosf(qa), sinf(qa));
  }
  __syncthreads();
  for (int idx = tid; idx < 1024; idx += 256) {
    int h = idx >> 7, d = idx & 127;
    int m = d >> 6, r = d & 63, c = r >> 4, e = r & 15;
    float qc = row[h * 64 + c * 16 + e];
    float qp = row[h * 64 + (c ^ 1) * 16 + e];
    float2 tg = trig[h][m];
    float sgn = (c == 0 || c == 3) ? -1.f : 1.f;
    Qr0bf[((size_t)h * 96 + l) * 128 + d] = f2bf(fmaf(qc, tg.x, sgn * qp * tg.y));
  }
}

// ---------------------------------------------------------------------------
// Build Kr0 bf16 [b*8+h][3072 s][128 d] from KF0 [24576][544] (layer-0 k-side).
// ---------------------------------------------------------------------------
__global__ __launch_bounds__(256)
void build_kr0(const float* __restrict__ KF0, ushort* __restrict__ Kr0) {
  const int rs = blockIdx.x;          // b*3072 + s
  const int b = rs / S_, s = rs - b * S_;
  const float* row = KF0 + (size_t)rs * NF;
  __shared__ float2 trig[8][2];
  const int tid = threadIdx.x;
  if (tid < 16) {
    int h = tid >> 1, m = tid & 1;
    float om = row[512 + h * 2 + m], th = row[528 + h * 2 + m];
    float ka = fmaf(om, (float)s * (1.f / (float)S_), th);
    trig[h][m] = make_float2(cosf(ka), sinf(ka));
  }
  __syncthreads();
  for (int idx = tid; idx < 512; idx += 256) {
    int h = idx >> 6, d = (idx & 63) * 2;
    int m = d >> 6, r = d & 63, c = r >> 4, e = r & 15;  // e even
    const float* rh = row + h * 64;
    float2 kc = *(const float2*)(rh + c * 16 + e);
    float2 kp = *(const float2*)(rh + (c ^ 2) * 16 + e);
    float2 tg = trig[h][m];
    float sgn = (c < 2) ? -1.f : 1.f;
    ushort2 u;
    u.x = f2bf(fmaf(kc.x, tg.x, sgn * kp.x * tg.y));
    u.y = f2bf(fmaf(kc.y, tg.x, sgn * kp.y * tg.y));
    *(ushort2*)&Kr0[(((size_t)(b * 8 + h)) * S_ + s) * 128 + d] = u;
  }
}

// ---------------------------------------------------------------------------
// Build Vt0 bf16 [b*8+h][64 d][3072 s] from V0b bf16 [24576][512].
// ---------------------------------------------------------------------------
__global__ __launch_bounds__(256)
void build_vt0(const ushort* __restrict__ V0b, ushort* __restrict__ Vt0) {
  const int st = blockIdx.x, h = blockIdx.y, b = blockIdx.z;
  const int s0 = st * 64;
  const int tid = threadIdx.x;
  __shared__ ushort T[64][68];
  for (int idx = tid; idx < 4096; idx += 256) {
    int s = idx >> 6, d = idx & 63;
    T[d][s] = V0b[((size_t)(b * S_ + s0 + s)) * 512 + h * 64 + d];
  }
  __syncthreads();
  for (int idx = tid; idx < 2048; idx += 256) {
    int d = idx >> 5, s2 = (idx & 31) * 2;
    ushort2 u = *(const ushort2*)&T[d][s2];
    *(ushort2*)&Vt0[(((size_t)(b * 8 + h)) * 64 + d) * S_ + s0 + s2] = u;
  }
}

// ---------------------------------------------------------------------------
// Build Kr1 bf16 [b*8+h][96 s][128 d] from KF1 [768][544] (layer-1 k-side).
// ---------------------------------------------------------------------------
__global__ __launch_bounds__(256)
void build_kr1(const float* __restrict__ KF1, ushort* __restrict__ Kr1b) {
  const int rs = blockIdx.x;
  const int b = rs / 96, s = rs % 96;
  const float* row = KF1 + (size_t)rs * NF;
  __shared__ float2 trig[8][2];
  const int tid = threadIdx.x;
  if (tid < 16) {
    int h = tid >> 1, m = tid & 1;
    float om = row[512 + h * 2 + m], th = row[528 + h * 2 + m];
    float ka = fmaf(om, (float)s / 96.f, th);
    trig[h][m] = make_float2(cosf(ka), sinf(ka));
  }
  __syncthreads();
  for (int idx = tid; idx < 512; idx += 256) {
    int h = idx >> 6, d = (idx & 63) * 2;
    int m = d >> 6, r = d & 63, c = r >> 4, e = r & 15;  // e even
    const float* rh = row + h * 64;
    float2 kc = *(const float2*)(rh + c * 16 + e);
    float2 kp = *(const float2*)(rh + (c ^ 2) * 16 + e);
    float2 tg = trig[h][m];
    float sgn = (c < 2) ? -1.f : 1.f;
    ushort2 u;
    u.x = f2bf(fmaf(kc.x, tg.x, sgn * kp.x * tg.y));
    u.y = f2bf(fmaf(kc.y, tg.x, sgn * kp.y * tg.y));
    *(ushort2*)&Kr1b[(((size_t)(b * 8 + h)) * 96 + s) * 128 + d] = u;
  }
}

// ---------------------------------------------------------------------------
// Build Qr1 bf16 [b*8+h][3072 l][128 d] from QF1 [24576][544] (layer-1 q-side).
// ---------------------------------------------------------------------------
__global__ __launch_bounds__(256)
void build_qr1(const float* __restrict__ QF1, ushort* __restrict__ Qr1) {
  const int rl = blockIdx.x;          // b*3072 + l
  const int b = rl / L_, l = rl - b * L_;
  const float* row = QF1 + (size_t)rl * NF;
  __shared__ float2 trig[8][2];
  const int tid = threadIdx.x;
  if (tid < 16) {
    int h = tid >> 1, m = tid & 1;
    float om = row[512 + h * 2 + m], th = row[528 + h * 2 + m];
    float qa = fmaf(om, (float)l * (1.f / (float)L_), th);
    trig[h][m] = make_float2(cosf(qa), sinf(qa));
  }
  __syncthreads();
  for (int idx = tid; idx < 512; idx += 256) {
    int h = idx >> 6, d = (idx & 63) * 2;
    int m = d >> 6, r = d & 63, c = r >> 4, e = r & 15;  // e even
    const float* rh = row + h * 64;
    float2 qc = *(const float2*)(rh + c * 16 + e);
    float2 qp = *(const float2*)(rh + (c ^ 1) * 16 + e);
    float2 tg = trig[h][m];
    float sgn = (c == 0 || c == 3) ? -1.f : 1.f;
    ushort2 u;
    u.x = f2bf(fmaf(qc.x, tg.x, sgn * qp.x * tg.y));
    u.y = f2bf(fmaf(qc.y, tg.x, sgn * qp.y * tg.y));
    *(ushort2*)&Qr1[(((size_t)(b * 8 + h)) * L_ + l) * 128 + d] = u;
  }
}

// ---------------------------------------------------------------------------
// Build Vt1 bf16 [b*8+h][64 d][96 s] from V1 fp32 [768][512].
// ---------------------------------------------------------------------------
__global__ __launch_bounds__(256)
void build_vt1(const float* __restrict__ V1, ushort* __restrict__ Vt1) {
  const int h = blockIdx.x, b = blockIdx.y;
  const int tid = threadIdx.x;
  __shared__ ushort T[64][104];
  for (int idx = tid; idx < 96 * 64; idx += 256) {
    int s = idx >> 6, d = idx & 63;
    T[d][s] = f2bf(V1[(size_t)(b * 96 + s) * 512 + h * 64 + d]);
  }
  __syncthreads();
  for (int idx = tid; idx < 64 * 12; idx += 256) {
    int d = idx / 12, c8 = (idx % 12) * 8;
    *(uint4*)&Vt1[(((size_t)(b * 8 + h)) * 64 + d) * 96 + c8] = *(const uint4*)&T[d][c8];
  }
}

// ---------------------------------------------------------------------------
// Layer-0 attention, MFMA (unchanged from R4: per-wave K/V register preload
// with sched_barrier pin; attn0 is below the profiling visibility line).
// grid (8 sc, 8 h, 8 b), 256 threads.
// ---------------------------------------------------------------------------
__global__ __launch_bounds__(256)
void attn0_mfma(const ushort* __restrict__ Kr0, const ushort* __restrict__ Vt0,
                const ushort* __restrict__ Qr0bf, float* __restrict__ accP,
                float* __restrict__ sumP) {
  const int sc = blockIdx.x, h = blockIdx.y, b = blockIdx.z;
  const int tid = threadIdx.x;
  const int wv = tid >> 6, lane = tid & 63, quad = lane >> 4, col = lane & 15;

  __shared__ __align__(16) ushort Qs[96][136];
  __shared__ __align__(16) ushort Ps[96][72];
  __shared__ float rowsum[96];

  const int s0g = sc * SCHUNK;
  const ushort* Kb = Kr0 + ((size_t)(b * 8 + h) * S_ + s0g) * 128;
  const ushort* Vb = Vt0 + ((size_t)(b * 8 + h)) * 64 * S_ + s0g;

  bf16x8 bk[6][4];
#pragma unroll
  for (int t = 0; t < 6; ++t) {
    const ushort* Kt = Kb + ((size_t)(t * 64 + wv * 16 + col)) * 128;
#pragma unroll
    for (int k = 0; k < 4; ++k) bk[t][k] = *(const bf16x8*)(Kt + k * 32 + quad * 8);
  }
  bf16x8 bv[6][2];
  {
    const ushort* Vt = Vb + ((size_t)(wv * 16 + col)) * S_;
#pragma unroll
    for (int t = 0; t < 6; ++t) {
      bv[t][0] = *(const bf16x8*)(Vt + t * 64 + quad * 8);
      bv[t][1] = *(const bf16x8*)(Vt + t * 64 + 32 + quad * 8);
    }
  }
  __builtin_amdgcn_sched_barrier(0);

  const ushort* Qg = Qr0bf + (size_t)h * 96 * 128;
  for (int idx = tid; idx < 96 * 16; idx += 256) {
    int l = idx >> 4, c8 = (idx & 15) * 8;
    *(uint4*)&Qs[l][c8] = *(const uint4*)(Qg + (size_t)l * 128 + c8);
  }
  if (tid < 96) rowsum[tid] = 0.f;

  f32x4 oacc[6];
#pragma unroll
  for (int i = 0; i < 6; ++i) {
    f32x4 z = {0.f, 0.f, 0.f, 0.f};
    oacc[i] = z;
  }

  __syncthreads();  // Qs + rowsum ready

#pragma unroll
  for (int t = 0; t < 6; ++t) {
    f32x4 sacc[6];
#pragma unroll
    for (int mt = 0; mt < 6; ++mt) {
      f32x4 z = {0.f, 0.f, 0.f, 0.f};
      sacc[mt] = z;
#pragma unroll
      for (int k = 0; k < 4; ++k) {
        bf16x8 a = *(const bf16x8*)&Qs[mt * 16 + col][k * 32 + quad * 8];
        sacc[mt] = mfma16(a, bk[t][k], sacc[mt]);
      }
    }
#pragma unroll
    for (int mt = 0; mt < 6; ++mt) {
      float pr[4];
#pragma unroll
      for (int r = 0; r < 4; ++r) {
        float p = __expf(sacc[mt][r] * 0.0625f);
        pr[r] = p;
        Ps[mt * 16 + quad * 4 + r][wv * 16 + col] = f2bf(p);
      }
#pragma unroll
      for (int r = 0; r < 4; ++r) {
#pragma unroll
        for (int off = 1; off < 16; off <<= 1) pr[r] += __shfl_xor(pr[r], off);
      }
      if (col == 0) {
#pragma unroll
        for (int r = 0; r < 4; ++r)
          atomicAdd(&rowsum[mt * 16 + quad * 4 + r], pr[r]);
      }
    }
    __syncthreads();  // Ps visible to all waves
#pragma unroll
    for (int mt = 0; mt < 6; ++mt) {
      bf16x8 a0 = *(const bf16x8*)&Ps[mt * 16 + col][quad * 8];
      oacc[mt] = mfma16(a0, bv[t][0], oacc[mt]);
      bf16x8 a1 = *(const bf16x8*)&Ps[mt * 16 + col][32 + quad * 8];
      oacc[mt] = mfma16(a1, bv[t][1], oacc[mt]);
    }
    __syncthreads();  // Ps reads done before next iter overwrites
  }
  const size_t pbase = (((size_t)(b * 8 + h)) * NSC + sc) * 96;
#pragma unroll
  for (int mt = 0; mt < 6; ++mt) {
#pragma unroll
    for (int r = 0; r < 4; ++r) {
      int l = mt * 16 + quad * 4 + r;
      accP[(pbase + l) * 64 + wv * 16 + col] = oacc[mt][r];
    }
  }
  if (tid < 96) sumP[pbase + tid] = rowsum[tid];
}

// Stage 2: combine the NSC chunk partials -> attn0 [b*96+l][h*64+d]
__global__ __launch_bounds__(256)
void attn0_stage2(const float* __restrict__ accP, const float* __restrict__ sumP,
                  float* __restrict__ attn0) {
  const int l = blockIdx.x, b = blockIdx.y;
  const int tid = threadIdx.x;
  for (int e = tid; e < 512; e += 256) {
    int h = e >> 6, d = e & 63;
    size_t base = ((size_t)(b * 8 + h)) * NSC * 96;
    float num = 0.f, den = 0.f;
    for (int scv = 0; scv < NSC; ++scv) {
      size_t pb = base + (size_t)scv * 96 + l;
      num += accP[pb * 64 + d];
      den += sumP[pb];
    }
    attn0[((size_t)(b * 96 + l)) * 512 + e] = num / den;
  }
}

// ---------------------------------------------------------------------------
// trend_norm: moving_avg(k=25, edge-replicated) -> LayerNorm(seasonal) + trend
// ---------------------------------------------------------------------------
__global__ __launch_bounds__(256)
void trend_norm(const float* __restrict__ y, const float* __restrict__ g,
                const float* __restrict__ be, float* __restrict__ outp) {
  const int t = blockIdx.x, b = blockIdx.y;
  const int tid = threadIdx.x;
  __shared__ float red[256];
  __shared__ float red2[256];
  float seas[2], trend[2];
  float lsum = 0.f, lsum2 = 0.f;
#pragma unroll
  for (int u = 0; u < 2; ++u) {
    int d = tid + u * 256;
    float tr = 0.f;
    for (int j = -12; j <= 12; ++j) {
      int tt = t + j;
      tt = tt < 0 ? 0 : (tt > 95 ? 95 : tt);
      tr += y[((size_t)(b * 96 + tt)) * 512 + d];
    }
    tr *= (1.f / 25.f);
    float x = y[((size_t)(b * 96 + t)) * 512 + d];
    float se = x - tr;
    seas[u] = se;
    trend[u] = tr;
    lsum += se;
    lsum2 += se * se;
  }
  red[tid] = lsum;
  red2[tid] = lsum2;
  __syncthreads();
  for (int off = 128; off > 0; off >>= 1) {
    if (tid < off) {
      red[tid] += red[tid + off];
      red2[tid] += red2[tid + off];
    }
    __syncthreads();
  }
  float mu = red[0] / 512.f;
  float var = red2[0] / 512.f - mu * mu;
  float rs = rsqrtf(var + 1e-5f);
#pragma unroll
  for (int u = 0; u < 2; ++u) {
    int d = tid + u * 256;
    outp[((size_t)(b * 96 + t)) * 512 + d] = (seas[u] - mu) * rs * g[d] + be[d] + trend[u];
  }
}

// ---------------------------------------------------------------------------
// Penalty: sum(diff(om, axis=seq)^2) and sum(th^2) over a fused proj buffer.
// ---------------------------------------------------------------------------
__global__ __launch_bounds__(256)
void penalty(const float* __restrict__ base, int R, int nb, float mult,
             float* __restrict__ pen) {
  const int tid = threadIdx.x;
  size_t gid = (size_t)blockIdx.x * 256 + tid;
  size_t total = (size_t)nb * R * 16;
  float omv = 0.f, thv = 0.f;
  if (gid < total) {
    int j = (int)(gid & 15);
    size_t row = gid >> 4;
    int s = (int)(row % R);
    const float* r0 = base + row * NF;
    float th = r0[528 + j];
    thv = th * th;
    if (s < R - 1) {
      float d = r0[NF + 512 + j] - r0[512 + j];
      omv = d * d;
    }
  }
  __shared__ float ro[256], rt[256];
  ro[tid] = omv;
  rt[tid] = thv;
  __syncthreads();
  for (int off = 128; off > 0; off >>= 1) {
    if (tid < off) {
      ro[tid] += ro[tid + off];
      rt[tid] += rt[tid + off];
    }
    __syncthreads();
  }
  if (tid == 0) {
    atomicAdd(pen + 0, mult * ro[0]);
    atomicAdd(pen + 1, mult * rt[0]);
  }
}

// ---------------------------------------------------------------------------
// Layer-1 attention, MFMA. K,V are reused by ALL 4 waves -> stage them in LDS
// with contiguous uint4 copies (1KB/wave-instruction; fixes the 16-segment
// scattered fragment loads that TA-throughput-bound R2-R4 at ~53us). Q stays
// direct (4 loads, no reuse). Output goes through an LDS transpose (aliased
// onto dead Ks) for 128B-segment stores. grid (48 lt, 8h, 8b).
// ---------------------------------------------------------------------------
__global__ __launch_bounds__(256)
void attn1_mfma(const ushort* __restrict__ Qr1, const ushort* __restrict__ Kr1b,
                const ushort* __restrict__ Vt1, ushort* __restrict__ attn1) {
  const int nwg = gridDim.x * gridDim.y * gridDim.z;
  const int flat = (blockIdx.z * gridDim.y + blockIdx.y) * gridDim.x + blockIdx.x;
  const int nf = xcd_swizzle(flat, nwg);
  const int lt = nf % gridDim.x;
  const int rest = nf / gridDim.x;
  const int h = rest % gridDim.y, b = rest / gridDim.y;
  const int l0 = lt * 64;
  const int tid = threadIdx.x;
  const int wv = tid >> 6, lane = tid & 63, quad = lane >> 4, col = lane & 15;

  __shared__ __align__(16) ushort Ks[96][136];  // 26.1 KB
  __shared__ __align__(16) ushort Vs[64][104];  // 13.3 KB
  __shared__ __align__(16) ushort Ps[64][104];  // 13.3 KB  (total 52.7 KB)
  // Os aliases Ks (dead after QK^T; all waves past the Ps barrier are done
  // with Ks since Ps writes depend on all Ks reads).
  ushort(*Os)[72] = reinterpret_cast<ushort(*)[72]>(&Ks[0][0]);

  const ushort* Qg = Qr1 + ((size_t)(b * 8 + h) * L_ + l0) * 128;
  const ushort* Kg = Kr1b + (size_t)(b * 8 + h) * 96 * 128;
  const ushort* Vg = Vt1 + (size_t)(b * 8 + h) * 64 * 96;

  // Coalesced cooperative staging of the wave-shared operands.
  for (int idx = tid; idx < 96 * 16; idx += 256) {
    int r = idx >> 4, c8 = (idx & 15) * 8;
    *(uint4*)&Ks[r][c8] = *(const uint4*)(Kg + (size_t)r * 128 + c8);
  }
  for (int idx = tid; idx < 64 * 12; idx += 256) {
    int r = idx / 12, c8 = (idx % 12) * 8;
    *(uint4*)&Vs[r][c8] = *(const uint4*)(Vg + (size_t)r * 96 + c8);
  }
  // Q fragments: private per wave, direct loads (4 per thread).
  bf16x8 aq[4];
#pragma unroll
  for (int k = 0; k < 4; ++k)
    aq[k] = *(const bf16x8*)(Qg + ((size_t)(wv * 16 + col)) * 128 + k * 32 + quad * 8);
  __syncthreads();

  f32x4 sacc[6];
#pragma unroll
  for (int nt = 0; nt < 6; ++nt) {
    f32x4 z = {0.f, 0.f, 0.f, 0.f};
    sacc[nt] = z;
#pragma unroll
    for (int k = 0; k < 4; ++k) {
      bf16x8 bkf = *(const bf16x8*)&Ks[nt * 16 + col][k * 32 + quad * 8];
      sacc[nt] = mfma16(aq[k], bkf, sacc[nt]);
    }
  }
  float rsum[4] = {0.f, 0.f, 0.f, 0.f};
#pragma unroll
  for (int nt = 0; nt < 6; ++nt) {
#pragma unroll
    for (int r = 0; r < 4; ++r) {
      float p = __expf(sacc[nt][r] * 0.0625f);
      Ps[wv * 16 + quad * 4 + r][nt * 16 + col] = f2bf(p);
      rsum[r] += p;
    }
  }
#pragma unroll
  for (int r = 0; r < 4; ++r) {
#pragma unroll
    for (int off = 1; off < 16; off <<= 1) rsum[r] += __shfl_xor(rsum[r], off);
  }
  __syncthreads();  // Ps complete (implies all Ks reads done -> Os safe)
  bf16x8 ap[3];
#pragma unroll
  for (int kt = 0; kt < 3; ++kt)
    ap[kt] = *(const bf16x8*)&Ps[wv * 16 + col][kt * 32 + quad * 8];
  f32x4 oacc[4];
#pragma unroll
  for (int nt = 0; nt < 4; ++nt) {
    f32x4 z = {0.f, 0.f, 0.f, 0.f};
    oacc[nt] = z;
#pragma unroll
    for (int kt = 0; kt < 3; ++kt) {
      bf16x8 bvf = *(const bf16x8*)&Vs[nt * 16 + col][kt * 32 + quad * 8];
      oacc[nt] = mfma16(ap[kt], bvf, oacc[nt]);
    }
  }
  float inv[4];
#pragma unroll
  for (int r = 0; r < 4; ++r) inv[r] = 1.f / rsum[r];
#pragma unroll
  for (int nt = 0; nt < 4; ++nt) {
#pragma unroll
    for (int r = 0; r < 4; ++r) {
      Os[wv * 16 + quad * 4 + r][nt * 16 + col] = f2bf(oacc[nt][r] * inv[r]);
    }
  }
  __syncthreads();
  for (int idx = tid; idx < 64 * 8; idx += 256) {
    int l = idx >> 3, c8 = (idx & 7) * 8;
    *(uint4*)(attn1 + (size_t)(b * L_ + l0 + l) * 512 + h * 64 + c8) =
        *(const uint4*)&Os[l][c8];
  }
}

// ---------------------------------------------------------------------------
extern "C" void kernel_launch(void* const* d_in, const int* in_sizes, int n_in,
                              void* d_out, int out_size, void* d_ws, size_t ws_size,
                              hipStream_t stream) {
  (void)in_sizes; (void)n_in; (void)out_size; (void)ws_size;
  const float* queries = (const float*)d_in[0];
  const float* keys = (const float*)d_in[1];
  const float* values = (const float*)d_in[2];
  const float* Wq = (const float*)d_in[3];
  const float* bq = (const float*)d_in[4];
  const float* Wk = (const float*)d_in[5];
  const float* bk = (const float*)d_in[6];
  const float* Wv = (const float*)d_in[7];
  const float* bv = (const float*)d_in[8];
  const float* Wqo = (const float*)d_in[9];
  const float* bqo = (const float*)d_in[10];
  const float* Wko = (const float*)d_in[11];
  const float* bko = (const float*)d_in[12];
  const float* Wqt = (const float*)d_in[13];
  const float* bqt = (const float*)d_in[14];
  const float* Wkt = (const float*)d_in[15];
  const float* bkt = (const float*)d_in[16];
  const float* Wo = (const float*)d_in[17];
  const float* bo = (const float*)d_in[18];
  const float* I = (const float*)d_in[19];
  const float* ln_g = (const float*)d_in[20];
  const float* ln_b = (const float*)d_in[21];
  float* out = (float*)d_out;

  float* ws = (float*)d_ws;
  size_t off = 0;
  auto alloc = [&](size_t n) {
    float* p = ws + off;
    off += (n + 3) & ~(size_t)3;
    return p;
  };
  auto allocU = [&](size_t n) { return (ushort*)alloc((n + 1) / 2); };

  // fp32 packed weights (small-M gemms)
  float* WCAT0Q = alloc(512 * 544);
  float* WCAT1K = alloc(512 * 544);
  float* BCAT0Q = alloc(544);
  float* BCAT1K = alloc(544);
  // bf16 transposed weights (big gemms)
  ushort* BT0K = allocU(640 * 512);
  ushort* BT1Q = allocU(640 * 512);
  ushort* BTV0 = allocU(512 * 512);
  ushort* BTO1 = allocU(512 * 512);
  float* B0K = alloc(544);
  float* B1Q = alloc(544);
  float* BV0 = alloc(512);
  float* BO1 = alloc(512);
  float* pen = alloc(16);
  float* QF0 = alloc(96 * 544);
  ushort* Qr0bf = allocU(8 * 96 * 128);
  float* KF0 = alloc((size_t)24576 * 544);  // reused as QF1
  float* V0 = alloc((size_t)24576 * 512);   // bf16 V0 in first half; reused as Qr1
  float* attn0 = alloc(768 * 512);
  float* y0 = alloc(768 * 512);
  float* xind = alloc(768 * 512);
  float* KF1 = alloc(768 * 544);
  float* V1 = alloc(768 * 512);
  ushort* Kr1b = allocU((size_t)64 * 96 * 128);  // bf16 rotated K, layer 1
  ushort* Vt1 = allocU((size_t)64 * 64 * 96);    // bf16 transposed V, layer 1
  float* accP = alloc((size_t)64 * NSC * 96 * 64);
  float* sumP = alloc((size_t)64 * NSC * 96);
  // XB1/XB2 MUST stay adjacent: their union (2 x 12,582,912 ushorts) is
  // reused as Kr0 bf16 [64][3072][128] = 25,165,824 ushorts during attn0.
  ushort* XB1 = allocU((size_t)24576 * 512);  // keysB, then Kr0 lo, then queriesB
  ushort* XB2 = allocU((size_t)24576 * 512);  // valuesB, then Kr0 hi, then attn1 out
  ushort* Kr0U = XB1;
  ushort* Vt0U = allocU((size_t)64 * 64 * S_);  // 25.2 MB
  float* QF1 = KF0;
  ushort* V0b = (ushort*)V0;   // bf16 V0 [24576][512] (25 MB in the 50 MB region)
  ushort* Qr1U = (ushort*)V0;  // later: Qr1 bf16 (V0b dead after build_vt0)

  init_pen<<<1, 64, 0, stream>>>(pen);
  const int packBlocks = (512 * 544 + 255) / 256;
  pack_w<<<packBlocks, 256, 0, stream>>>(Wq, Wqo, Wqt, bq, bqo, bqt, WCAT0Q, BCAT0Q);
  pack_w<<<packBlocks, 256, 0, stream>>>(Wk + 262144, Wko + 8192, Wkt + 8192,
                                         bk + 512, bko + 16, bkt + 16, WCAT1K, BCAT1K);
  pack_wt_fused<<<(640 * 512 + 255) / 256, 256, 0, stream>>>(
      Wk, Wko, Wkt, bk, bko, bkt, BT0K, B0K);
  pack_wt_fused<<<(640 * 512 + 255) / 256, 256, 0, stream>>>(
      Wq + 262144, Wqo + 8192, Wqt + 8192, bq + 512, bqo + 16, bqt + 16, BT1Q, B1Q);
  pack_wt_plain<<<(512 * 512 + 255) / 256, 256, 0, stream>>>(Wv, bv, BTV0, BV0);
  pack_wt_plain<<<(512 * 512 + 255) / 256, 256, 0, stream>>>(Wo + 262144, bo + 512,
                                                             BTO1, BO1);
  const int castBlocks = (24576 * 512 / 8 + 255) / 256;
  cast_bf16<<<castBlocks, 256, 0, stream>>>(keys, XB1, 24576 * 512 / 8);
  cast_bf16<<<castBlocks, 256, 0, stream>>>(values, XB2, 24576 * 512 / 8);

  // ---- layer 0 ----
  gemm_bf16_mfma<<<dim3(5, 192), 256, 0, stream>>>(XB1, BT0K, B0K, KF0, 544, 544, 1, 0);
  gemm_bf16_mfma<<<dim3(4, 192), 256, 0, stream>>>(XB2, BTV0, BV0, V0b, 512, 512, 0, 1);
  gemm_k512<<<dim3(9, 2), 256, 0, stream>>>(I, WCAT0Q, BCAT0Q, QF0, 96, 544, 1);
  build_qr0<<<96, 256, 0, stream>>>(QF0, Qr0bf);
  penalty<<<(96 * 16 + 255) / 256, 256, 0, stream>>>(QF0, 96, 1, 8.f, pen);
  penalty<<<(24576 * 16 + 255) / 256, 256, 0, stream>>>(KF0, 3072, 8, 1.f, pen);
  build_kr0<<<24576, 256, 0, stream>>>(KF0, Kr0U);        // overwrites XB1+XB2
  build_vt0<<<dim3(48, 8, 8), 256, 0, stream>>>(V0b, Vt0U);
  attn0_mfma<<<dim3(8, 8, 8), 256, 0, stream>>>(Kr0U, Vt0U, Qr0bf, accP, sumP);
  attn0_stage2<<<dim3(96, 8), 256, 0, stream>>>(accP, sumP, attn0);
  gemm_k512<<<dim3(8, 12), 256, 0, stream>>>(attn0, Wo, bo, y0, 768, 512, 0);
  trend_norm<<<dim3(96, 8), 256, 0, stream>>>(y0, ln_g, ln_b, xind);

  // ---- layer 1 ----
  gemm_k512<<<dim3(9, 12), 256, 0, stream>>>(xind, WCAT1K, BCAT1K, KF1, 768, 544, 1);
  gemm_k512<<<dim3(8, 12), 256, 0, stream>>>(xind, Wv + 262144, bv + 512, V1, 768, 512, 0);
  build_kr1<<<768, 256, 0, stream>>>(KF1, Kr1b);
  build_vt1<<<dim3(8, 8), 256, 0, stream>>>(V1, Vt1);
  penalty<<<(768 * 16 + 255) / 256, 256, 0, stream>>>(KF1, 96, 8, 1.f, pen);
  cast_bf16<<<castBlocks, 256, 0, stream>>>(queries, XB1, 24576 * 512 / 8);
  gemm_bf16_mfma<<<dim3(5, 192), 256, 0, stream>>>(XB1, BT1Q, B1Q, QF1, 544, 544, 1, 0);
  penalty<<<(24576 * 16 + 255) / 256, 256, 0, stream>>>(QF1, 3072, 8, 1.f, pen);
  build_qr1<<<24576, 256, 0, stream>>>(QF1, Qr1U);        // overwrites V0b
  attn1_mfma<<<dim3(48, 8, 8), 256, 0, stream>>>(Qr1U, Kr1b, Vt1, XB2);
  gemm_bf16_mfma<<<dim3(4, 192), 256, 0, stream>>>(XB2, BTO1, BO1, out, 512, 512, 0, 0);
  write_pen<<<1, 64, 0, stream>>>(pen, out);
}

// Round 7
// 770.413 us; speedup vs baseline: 1.0348x; 1.0315x over previous
//
#include <hip/hip_runtime.h>
#include <math.h>

#define PI_F 3.14159265358979323846f

namespace {
constexpr int B_ = 8;
constexpr int L_ = 3072;
constexpr int S_ = 3072;
constexpr int H_ = 8;
constexpr int NF = 544;          // fused projection width: 512 (main) + 16 (omega) + 16 (theta)
constexpr int NSC = 8;           // s-chunks for layer-0 attention
constexpr int SCHUNK = S_ / NSC; // 384
}

typedef __attribute__((ext_vector_type(8))) short bf16x8;
typedef __attribute__((ext_vector_type(4))) float f32x4;

__device__ inline f32x4 mfma16(bf16x8 a, bf16x8 b, f32x4 c) {
  return __builtin_amdgcn_mfma_f32_16x16x32_bf16(a, b, c, 0, 0, 0);
}

__device__ inline ushort f2bf(float f) {
  union { float f; unsigned u; } v;
  v.f = f;
  unsigned r = v.u + 0x7FFFu + ((v.u >> 16) & 1u);
  return (ushort)(r >> 16);
}

// async global->LDS, 16B per lane; lds base must be wave-uniform.
__device__ inline void gl_lds16(const void* g, void* l) {
  __builtin_amdgcn_global_load_lds(
      (const __attribute__((address_space(1))) unsigned int*)g,
      (__attribute__((address_space(3))) unsigned int*)l, 16, 0, 0);
}

// Bijective XCD-chunked remap (T1, m204): consecutive new-ids land on one XCD.
__device__ inline int xcd_swizzle(int flat, int nwg) {
  int q = nwg >> 3, r = nwg & 7;
  int xcd = flat & 7, ix = flat >> 3;
  return (xcd < r ? xcd * (q + 1) : r * (q + 1) + (xcd - r) * q) + ix;
}

// ---------------------------------------------------------------------------
// misc small kernels
// ---------------------------------------------------------------------------
__global__ void init_pen(float* pen) {
  if (threadIdx.x < 16) pen[threadIdx.x] = 0.f;
}

__global__ void write_pen(const float* __restrict__ pen, float* __restrict__ out) {
  if (threadIdx.x == 0) out[12582912] = pen[0];
  if (threadIdx.x == 1) out[12582913] = pen[1];
}

// Pack Wmain[512,512] | Wom[512,16] | Wth[512,16] -> Wcat[512,544] fp32 (+bias)
__global__ void pack_w(const float* __restrict__ Wm, const float* __restrict__ Wo_,
                       const float* __restrict__ Wt, const float* __restrict__ bm,
                       const float* __restrict__ bo_, const float* __restrict__ bt,
                       float* __restrict__ Wcat, float* __restrict__ bcat) {
  int gid = blockIdx.x * 256 + threadIdx.x;
  if (gid < 512 * 544) {
    int k = gid / 544, n = gid % 544;
    float v;
    if (n < 512) v = Wm[(size_t)k * 512 + n];
    else if (n < 528) v = Wo_[k * 16 + (n - 512)];
    else v = Wt[k * 16 + (n - 528)];
    Wcat[gid] = v;
  }
  if (gid < 544) {
    float v;
    if (gid < 512) v = bm[gid];
    else if (gid < 528) v = bo_[gid - 512];
    else v = bt[gid - 528];
    bcat[gid] = v;
  }
}

// Transposed bf16 weight pack: BT[640][512], rows 544..639 zeroed; bias[544].
__global__ void pack_wt_fused(const float* __restrict__ Wm, const float* __restrict__ Wo_,
                              const float* __restrict__ Wt, const float* __restrict__ bm,
                              const float* __restrict__ bo_, const float* __restrict__ bt,
                              ushort* __restrict__ BT, float* __restrict__ bias) {
  int gid = blockIdx.x * 256 + threadIdx.x;
  if (gid < 640 * 512) {
    int n = gid >> 9, k = gid & 511;
    float v = 0.f;
    if (n < 512) v = Wm[(size_t)k * 512 + n];
    else if (n < 528) v = Wo_[k * 16 + (n - 512)];
    else if (n < 544) v = Wt[k * 16 + (n - 528)];
    BT[gid] = f2bf(v);
  }
  if (gid < 544)
    bias[gid] = (gid < 512) ? bm[gid] : (gid < 528 ? bo_[gid - 512] : bt[gid - 528]);
}

// Transposed bf16 weight pack, plain 512x512 + bias[512].
__global__ void pack_wt_plain(const float* __restrict__ W, const float* __restrict__ b,
                              ushort* __restrict__ BT, float* __restrict__ bias) {
  int gid = blockIdx.x * 256 + threadIdx.x;
  if (gid < 512 * 512) {
    int n = gid >> 9, k = gid & 511;
    BT[gid] = f2bf(W[(size_t)k * 512 + n]);
  }
  if (gid < 512) bias[gid] = b[gid];
}

// fp32 -> bf16 cast, 8 elems/thread
__global__ __launch_bounds__(256)
void cast_bf16(const float* __restrict__ src, ushort* __restrict__ dst, int n8) {
  int gid = blockIdx.x * 256 + threadIdx.x;
  if (gid < n8) {
    float4 a = ((const float4*)src)[(size_t)gid * 2];
    float4 b = ((const float4*)src)[(size_t)gid * 2 + 1];
    ushort u[8] = {f2bf(a.x), f2bf(a.y), f2bf(a.z), f2bf(a.w),
                   f2bf(b.x), f2bf(b.y), f2bf(b.z), f2bf(b.w)};
    ((uint4*)dst)[gid] = *(uint4*)u;
  }
}

// ---------------------------------------------------------------------------
// bf16 MFMA GEMM: C[M,Nout] = act(A[M,512]bf16 @ BT[Npad,512]bf16^T + bias)
// 128x128 tile, BK=32, 4 waves (2x2), DOUBLE-BUFFERED global_load_lds with a
// COUNTED-vmcnt 2-deep pipeline (catalog T4): wait vmcnt(4) -- only the
// current buffer's 4 loads -- while the next buffer's 4 stay in flight across
// both barriers and the whole MFMA section. Never drain to 0 in the loop.
// Pipeline trace verified: outstanding queue at iter i = {buf(i)@i-2,
// buf(i+1)@i-1} = 8; vmcnt(4) retires exactly buf(i)'s loads (in-order).
// M multiple of 128. XCD-chunked tile remap. obf=1 -> bf16 output.
// ---------------------------------------------------------------------------
__global__ __launch_bounds__(256)
void gemm_bf16_mfma(const ushort* __restrict__ A, const ushort* __restrict__ BT,
                    const float* __restrict__ bias, void* __restrict__ Cv,
                    int ldc, int Nout, int act, int obf) {
  __shared__ ushort As[2][128][32];
  __shared__ ushort Bs[2][128][32];
  const int tid = threadIdx.x;
  const int wv = tid >> 6, lane = tid & 63, quad = lane >> 4, col = lane & 15;
  const int wm = wv & 1, wn = wv >> 1;

  const int nwg = gridDim.x * gridDim.y;
  const int flat = blockIdx.y * gridDim.x + blockIdx.x;
  const int nf = xcd_swizzle(flat, nwg);
  const int bx = nf % gridDim.x, by = nf / gridDim.x;
  const int m0 = by * 128, n0 = bx * 128;

  const int srow = lane >> 2;        // 0..15 row within 16-row staging group
  const int scol = (lane & 3) * 8;   // ushort offset (16B granules)

  f32x4 acc[4][4];
#pragma unroll
  for (int i = 0; i < 4; ++i)
#pragma unroll
    for (int j = 0; j < 4; ++j) {
      f32x4 z = {0.f, 0.f, 0.f, 0.f};
      acc[i][j] = z;
    }

  const ushort* Ag = A + (size_t)(m0 + wv * 32) * 512;
  const ushort* Bg = BT + (size_t)(n0 + wv * 32) * 512;

  auto stage = [&](int bb, int k0) {
    gl_lds16(Ag + (size_t)srow * 512 + k0 + scol, &As[bb][wv * 32][0]);
    gl_lds16(Ag + (size_t)(srow + 16) * 512 + k0 + scol, &As[bb][wv * 32 + 16][0]);
    gl_lds16(Bg + (size_t)srow * 512 + k0 + scol, &Bs[bb][wv * 32][0]);
    gl_lds16(Bg + (size_t)(srow + 16) * 512 + k0 + scol, &Bs[bb][wv * 32 + 16][0]);
  };

  // prologue: fill both buffers (8 loads/wave in flight)
  stage(0, 0);
  stage(1, 32);

  for (int i = 0; i < 16; ++i) {
    const int cur = i & 1;
    // Wait only the CURRENT buffer's loads (oldest 4); the other buffer's 4
    // remain in flight through this whole iteration.
    if (i < 15) asm volatile("s_waitcnt vmcnt(4)" ::: "memory");
    else        asm volatile("s_waitcnt vmcnt(0)" ::: "memory");
    __builtin_amdgcn_s_barrier();   // all waves' cur-buffer writes landed
    bf16x8 av[4], bv[4];
#pragma unroll
    for (int mi = 0; mi < 4; ++mi)
      av[mi] = *(const bf16x8*)&As[cur][wm * 64 + mi * 16 + col][quad * 8];
#pragma unroll
    for (int ni = 0; ni < 4; ++ni)
      bv[ni] = *(const bf16x8*)&Bs[cur][wn * 64 + ni * 16 + col][quad * 8];
#pragma unroll
    for (int mi = 0; mi < 4; ++mi)
#pragma unroll
      for (int ni = 0; ni < 4; ++ni)
        acc[mi][ni] = mfma16(av[mi], bv[ni], acc[mi][ni]);
    // Keep the ds_reads/MFMAs above the barrier, then free cur for overwrite.
    __builtin_amdgcn_sched_barrier(0);
    __builtin_amdgcn_s_barrier();   // all reads of cur done -> safe to restage
    if (i < 14) stage(cur, (i + 2) * 32);
  }

  float* Cf = (float*)Cv;
  ushort* Cu = (ushort*)Cv;
#pragma unroll
  for (int mi = 0; mi < 4; ++mi) {
#pragma unroll
    for (int ni = 0; ni < 4; ++ni) {
      int n = n0 + wn * 64 + ni * 16 + col;
      if (n >= Nout) continue;
      float bs = bias[n];
#pragma unroll
      for (int r = 0; r < 4; ++r) {
        int m = m0 + wm * 64 + mi * 16 + quad * 4 + r;
        float v = acc[mi][ni][r] + bs;
        if (act && n >= 512) v = (n < 528) ? fmaxf(v, 0.f) : tanhf(v) * PI_F;
        if (obf) Cu[(size_t)m * ldc + n] = f2bf(v);
        else Cf[(size_t)m * ldc + n] = v;
      }
    }
  }
}

// ---------------------------------------------------------------------------
// Generic K=512 fp32 GEMM (kept for small-M dispatches).
// ---------------------------------------------------------------------------
__global__ __launch_bounds__(256)
void gemm_k512(const float* __restrict__ A, const float* __restrict__ W,
               const float* __restrict__ bias, float* __restrict__ C,
               int M, int N, int act) {
  __shared__ float As[16][68];
  __shared__ float Ws_[16][68];
  const int tid = threadIdx.x;
  const int tx = tid & 15, ty = tid >> 4;
  const int m0 = blockIdx.y * 64, n0 = blockIdx.x * 64;

  float acc[4][4];
#pragma unroll
  for (int i = 0; i < 4; ++i)
#pragma unroll
    for (int j = 0; j < 4; ++j) acc[i][j] = 0.f;

  const int arow = tid >> 2;
  const int acol4 = (tid & 3) * 4;
  const int wrow = tid >> 4;
  const int wcol4 = (tid & 15) * 4;

  for (int k0 = 0; k0 < 512; k0 += 16) {
    float4 av = make_float4(0.f, 0.f, 0.f, 0.f);
    int gm = m0 + arow;
    if (gm < M) av = *(const float4*)(A + (size_t)gm * 512 + k0 + acol4);
    As[acol4 + 0][arow] = av.x;
    As[acol4 + 1][arow] = av.y;
    As[acol4 + 2][arow] = av.z;
    As[acol4 + 3][arow] = av.w;
    float4 wv;
    int gn = n0 + wcol4;
    if (gn + 3 < N) {
      wv = *(const float4*)(W + (size_t)(k0 + wrow) * N + gn);
    } else {
      float tmp[4] = {0.f, 0.f, 0.f, 0.f};
      for (int u = 0; u < 4; ++u)
        if (gn + u < N) tmp[u] = W[(size_t)(k0 + wrow) * N + gn + u];
      wv = make_float4(tmp[0], tmp[1], tmp[2], tmp[3]);
    }
    *(float4*)&Ws_[wrow][wcol4] = wv;
    __syncthreads();
#pragma unroll
    for (int k = 0; k < 16; ++k) {
      float4 a4 = *(const float4*)&As[k][ty * 4];
      float4 b4 = *(const float4*)&Ws_[k][tx * 4];
      float a[4] = {a4.x, a4.y, a4.z, a4.w};
      float b[4] = {b4.x, b4.y, b4.z, b4.w};
#pragma unroll
      for (int i = 0; i < 4; ++i)
#pragma unroll
        for (int j = 0; j < 4; ++j) acc[i][j] = fmaf(a[i], b[j], acc[i][j]);
    }
    __syncthreads();
  }

#pragma unroll
  for (int i = 0; i < 4; ++i) {
    int gm = m0 + ty * 4 + i;
    if (gm >= M) continue;
#pragma unroll
    for (int j = 0; j < 4; ++j) {
      int gn = n0 + tx * 4 + j;
      if (gn >= N) continue;
      float v = acc[i][j] + bias[gn];
      if (act && gn >= 512) v = (gn < 528) ? fmaxf(v, 0.f) : tanhf(v) * PI_F;
      C[(size_t)gm * N + gn] = v;
    }
  }
}

// ---------------------------------------------------------------------------
// Build Qr0 bf16 [8h][96l][128d] from QF0 [96][544] (layer-0 q-side).
// ---------------------------------------------------------------------------
__global__ __launch_bounds__(256)
void build_qr0(const float* __restrict__ QF0, ushort* __restrict__ Qr0bf) {
  const int l = blockIdx.x;
  const float* row = QF0 + (size_t)l * NF;
  __shared__ float2 trig[8][2];
  const int tid = threadIdx.x;
  if (tid < 16) {
    int h = tid >> 1, m = tid & 1;
    float om = row[512 + h * 2 + m], th = row[528 + h * 2 + m];
    float qa = fmaf(om, (float)l / 96.f, th);
    trig[h][m] = make_float2(cosf(qa), sinf(qa));
  }
  __syncthreads();
  for (int idx = tid; idx < 1024; idx += 256) {
    int h = idx >> 7, d = idx & 127;
    int m = d >> 6, r = d & 63, c = r >> 4, e = r & 15;
    float qc = row[h * 64 + c * 16 + e];
    float qp = row[h * 64 + (c ^ 1) * 16 + e];
    float2 tg = trig[h][m];
    float sgn = (c == 0 || c == 3) ? -1.f : 1.f;
    Qr0bf[((size_t)h * 96 + l) * 128 + d] = f2bf(fmaf(qc, tg.x, sgn * qp * tg.y));
  }
}

// ---------------------------------------------------------------------------
// Build Kr0 bf16 [b*8+h][3072 s][128 d] from KF0 [24576][544] (layer-0 k-side).
// ---------------------------------------------------------------------------
__global__ __launch_bounds__(256)
void build_kr0(const float* __restrict__ KF0, ushort* __restrict__ Kr0) {
  const int rs = blockIdx.x;          // b*3072 + s
  const int b = rs / S_, s = rs - b * S_;
  const float* row = KF0 + (size_t)rs * NF;
  __shared__ float2 trig[8][2];
  const int tid = threadIdx.x;
  if (tid < 16) {
    int h = tid >> 1, m = tid & 1;
    float om = row[512 + h * 2 + m], th = row[528 + h * 2 + m];
    float ka = fmaf(om, (float)s * (1.f / (float)S_), th);
    trig[h][m] = make_float2(cosf(ka), sinf(ka));
  }
  __syncthreads();
  for (int idx = tid; idx < 512; idx += 256) {
    int h = idx >> 6, d = (idx & 63) * 2;
    int m = d >> 6, r = d & 63, c = r >> 4, e = r & 15;  // e even
    const float* rh = row + h * 64;
    float2 kc = *(const float2*)(rh + c * 16 + e);
    float2 kp = *(const float2*)(rh + (c ^ 2) * 16 + e);
    float2 tg = trig[h][m];
    float sgn = (c < 2) ? -1.f : 1.f;
    ushort2 u;
    u.x = f2bf(fmaf(kc.x, tg.x, sgn * kp.x * tg.y));
    u.y = f2bf(fmaf(kc.y, tg.x, sgn * kp.y * tg.y));
    *(ushort2*)&Kr0[(((size_t)(b * 8 + h)) * S_ + s) * 128 + d] = u;
  }
}

// ---------------------------------------------------------------------------
// Build Vt0 bf16 [b*8+h][64 d][3072 s] from V0b bf16 [24576][512].
// ---------------------------------------------------------------------------
__global__ __launch_bounds__(256)
void build_vt0(const ushort* __restrict__ V0b, ushort* __restrict__ Vt0) {
  const int st = blockIdx.x, h = blockIdx.y, b = blockIdx.z;
  const int s0 = st * 64;
  const int tid = threadIdx.x;
  __shared__ ushort T[64][68];
  for (int idx = tid; idx < 4096; idx += 256) {
    int s = idx >> 6, d = idx & 63;
    T[d][s] = V0b[((size_t)(b * S_ + s0 + s)) * 512 + h * 64 + d];
  }
  __syncthreads();
  for (int idx = tid; idx < 2048; idx += 256) {
    int d = idx >> 5, s2 = (idx & 31) * 2;
    ushort2 u = *(const ushort2*)&T[d][s2];
    *(ushort2*)&Vt0[(((size_t)(b * 8 + h)) * 64 + d) * S_ + s0 + s2] = u;
  }
}

// ---------------------------------------------------------------------------
// Build Kr1 bf16 [b*8+h][96 s][128 d] from KF1 [768][544] (layer-1 k-side).
// ---------------------------------------------------------------------------
__global__ __launch_bounds__(256)
void build_kr1(const float* __restrict__ KF1, ushort* __restrict__ Kr1b) {
  const int rs = blockIdx.x;
  const int b = rs / 96, s = rs % 96;
  const float* row = KF1 + (size_t)rs * NF;
  __shared__ float2 trig[8][2];
  const int tid = threadIdx.x;
  if (tid < 16) {
    int h = tid >> 1, m = tid & 1;
    float om = row[512 + h * 2 + m], th = row[528 + h * 2 + m];
    float ka = fmaf(om, (float)s / 96.f, th);
    trig[h][m] = make_float2(cosf(ka), sinf(ka));
  }
  __syncthreads();
  for (int idx = tid; idx < 512; idx += 256) {
    int h = idx >> 6, d = (idx & 63) * 2;
    int m = d >> 6, r = d & 63, c = r >> 4, e = r & 15;  // e even
    const float* rh = row + h * 64;
    float2 kc = *(const float2*)(rh + c * 16 + e);
    float2 kp = *(const float2*)(rh + (c ^ 2) * 16 + e);
    float2 tg = trig[h][m];
    float sgn = (c < 2) ? -1.f : 1.f;
    ushort2 u;
    u.x = f2bf(fmaf(kc.x, tg.x, sgn * kp.x * tg.y));
    u.y = f2bf(fmaf(kc.y, tg.x, sgn * kp.y * tg.y));
    *(ushort2*)&Kr1b[(((size_t)(b * 8 + h)) * 96 + s) * 128 + d] = u;
  }
}

// ---------------------------------------------------------------------------
// Build Qr1 bf16 [b*8+h][3072 l][128 d] from QF1 [24576][544] (layer-1 q-side).
// ---------------------------------------------------------------------------
__global__ __launch_bounds__(256)
void build_qr1(const float* __restrict__ QF1, ushort* __restrict__ Qr1) {
  const int rl = blockIdx.x;          // b*3072 + l
  const int b = rl / L_, l = rl - b * L_;
  const float* row = QF1 + (size_t)rl * NF;
  __shared__ float2 trig[8][2];
  const int tid = threadIdx.x;
  if (tid < 16) {
    int h = tid >> 1, m = tid & 1;
    float om = row[512 + h * 2 + m], th = row[528 + h * 2 + m];
    float qa = fmaf(om, (float)l * (1.f / (float)L_), th);
    trig[h][m] = make_float2(cosf(qa), sinf(qa));
  }
  __syncthreads();
  for (int idx = tid; idx < 512; idx += 256) {
    int h = idx >> 6, d = (idx & 63) * 2;
    int m = d >> 6, r = d & 63, c = r >> 4, e = r & 15;  // e even
    const float* rh = row + h * 64;
    float2 qc = *(const float2*)(rh + c * 16 + e);
    float2 qp = *(const float2*)(rh + (c ^ 1) * 16 + e);
    float2 tg = trig[h][m];
    float sgn = (c == 0 || c == 3) ? -1.f : 1.f;
    ushort2 u;
    u.x = f2bf(fmaf(qc.x, tg.x, sgn * qp.x * tg.y));
    u.y = f2bf(fmaf(qc.y, tg.x, sgn * qp.y * tg.y));
    *(ushort2*)&Qr1[(((size_t)(b * 8 + h)) * L_ + l) * 128 + d] = u;
  }
}

// ---------------------------------------------------------------------------
// Build Vt1 bf16 [b*8+h][64 d][96 s] from V1 fp32 [768][512].
// ---------------------------------------------------------------------------
__global__ __launch_bounds__(256)
void build_vt1(const float* __restrict__ V1, ushort* __restrict__ Vt1) {
  const int h = blockIdx.x, b = blockIdx.y;
  const int tid = threadIdx.x;
  __shared__ ushort T[64][104];
  for (int idx = tid; idx < 96 * 64; idx += 256) {
    int s = idx >> 6, d = idx & 63;
    T[d][s] = f2bf(V1[(size_t)(b * 96 + s) * 512 + h * 64 + d]);
  }
  __syncthreads();
  for (int idx = tid; idx < 64 * 12; idx += 256) {
    int d = idx / 12, c8 = (idx % 12) * 8;
    *(uint4*)&Vt1[(((size_t)(b * 8 + h)) * 64 + d) * 96 + c8] = *(const uint4*)&T[d][c8];
  }
}

// ---------------------------------------------------------------------------
// Layer-0 attention, MFMA. Cooperative COALESCED LDS staging of K/V tiles
// (uint4, 1KB/wave-instruction) -- same fix that unstuck attn1 in R5; the
// R3/R4 per-lane scattered fragment loads were TA-throughput-bound.
// grid (8 sc, 8 h, 8 b), 256 threads.
// ---------------------------------------------------------------------------
__global__ __launch_bounds__(256)
void attn0_mfma(const ushort* __restrict__ Kr0, const ushort* __restrict__ Vt0,
                const ushort* __restrict__ Qr0bf, float* __restrict__ accP,
                float* __restrict__ sumP) {
  const int sc = blockIdx.x, h = blockIdx.y, b = blockIdx.z;
  const int tid = threadIdx.x;
  const int wv = tid >> 6, lane = tid & 63, quad = lane >> 4, col = lane & 15;

  __shared__ __align__(16) ushort Qs[96][136];
  __shared__ __align__(16) ushort Ks[64][136];
  __shared__ __align__(16) ushort Vt[64][72];
  __shared__ __align__(16) ushort Ps[96][72];
  __shared__ float rowsum[96];

  // Stage Q tile (96x128 bf16) once; reused over all 6 t-iterations.
  const ushort* Qg = Qr0bf + (size_t)h * 96 * 128;
  for (int idx = tid; idx < 96 * 16; idx += 256) {
    int l = idx >> 4, c8 = (idx & 15) * 8;
    *(uint4*)&Qs[l][c8] = *(const uint4*)(Qg + (size_t)l * 128 + c8);
  }
  if (tid < 96) rowsum[tid] = 0.f;

  f32x4 oacc[6];
#pragma unroll
  for (int i = 0; i < 6; ++i) {
    f32x4 z = {0.f, 0.f, 0.f, 0.f};
    oacc[i] = z;
  }

  const int s0g = sc * SCHUNK;
  const ushort* Kb = Kr0 + ((size_t)(b * 8 + h) * S_ + s0g) * 128;
  const ushort* Vb = Vt0 + ((size_t)(b * 8 + h)) * 64 * S_ + s0g;

  for (int t = 0; t < 6; ++t) {
    __syncthreads();  // prev iter's Ks/Vt/Ps reads done before overwrite
    for (int idx = tid; idx < 64 * 16; idx += 256) {
      int s = idx >> 4, c8 = (idx & 15) * 8;
      *(uint4*)&Ks[s][c8] = *(const uint4*)(Kb + ((size_t)(t * 64 + s)) * 128 + c8);
    }
    for (int idx = tid; idx < 64 * 8; idx += 256) {
      int d = idx >> 3, c8 = (idx & 7) * 8;
      *(uint4*)&Vt[d][c8] = *(const uint4*)(Vb + (size_t)d * S_ + t * 64 + c8);
    }
    __syncthreads();
    bf16x8 bk[4];
#pragma unroll
    for (int k = 0; k < 4; ++k)
      bk[k] = *(const bf16x8*)&Ks[wv * 16 + col][k * 32 + quad * 8];
    f32x4 sacc[6];
#pragma unroll
    for (int mt = 0; mt < 6; ++mt) {
      f32x4 z = {0.f, 0.f, 0.f, 0.f};
      sacc[mt] = z;
#pragma unroll
      for (int k = 0; k < 4; ++k) {
        bf16x8 a = *(const bf16x8*)&Qs[mt * 16 + col][k * 32 + quad * 8];
        sacc[mt] = mfma16(a, bk[k], sacc[mt]);
      }
    }
#pragma unroll
    for (int mt = 0; mt < 6; ++mt) {
      float pr[4];
#pragma unroll
      for (int r = 0; r < 4; ++r) {
        float p = __expf(sacc[mt][r] * 0.0625f);
        pr[r] = p;
        Ps[mt * 16 + quad * 4 + r][wv * 16 + col] = f2bf(p);
      }
#pragma unroll
      for (int r = 0; r < 4; ++r) {
#pragma unroll
        for (int off = 1; off < 16; off <<= 1) pr[r] += __shfl_xor(pr[r], off);
      }
      if (col == 0) {
#pragma unroll
        for (int r = 0; r < 4; ++r)
          atomicAdd(&rowsum[mt * 16 + quad * 4 + r], pr[r]);
      }
    }
    __syncthreads();  // Ps visible to all waves
    bf16x8 bv0 = *(const bf16x8*)&Vt[wv * 16 + col][quad * 8];
    bf16x8 bv1 = *(const bf16x8*)&Vt[wv * 16 + col][32 + quad * 8];
#pragma unroll
    for (int mt = 0; mt < 6; ++mt) {
      bf16x8 a0 = *(const bf16x8*)&Ps[mt * 16 + col][quad * 8];
      oacc[mt] = mfma16(a0, bv0, oacc[mt]);
      bf16x8 a1 = *(const bf16x8*)&Ps[mt * 16 + col][32 + quad * 8];
      oacc[mt] = mfma16(a1, bv1, oacc[mt]);
    }
  }
  __syncthreads();
  const size_t pbase = (((size_t)(b * 8 + h)) * NSC + sc) * 96;
#pragma unroll
  for (int mt = 0; mt < 6; ++mt) {
#pragma unroll
    for (int r = 0; r < 4; ++r) {
      int l = mt * 16 + quad * 4 + r;
      accP[(pbase + l) * 64 + wv * 16 + col] = oacc[mt][r];
    }
  }
  if (tid < 96) sumP[pbase + tid] = rowsum[tid];
}

// Stage 2: combine the NSC chunk partials -> attn0 [b*96+l][h*64+d]
__global__ __launch_bounds__(256)
void attn0_stage2(const float* __restrict__ accP, const float* __restrict__ sumP,
                  float* __restrict__ attn0) {
  const int l = blockIdx.x, b = blockIdx.y;
  const int tid = threadIdx.x;
  for (int e = tid; e < 512; e += 256) {
    int h = e >> 6, d = e & 63;
    size_t base = ((size_t)(b * 8 + h)) * NSC * 96;
    float num = 0.f, den = 0.f;
    for (int scv = 0; scv < NSC; ++scv) {
      size_t pb = base + (size_t)scv * 96 + l;
      num += accP[pb * 64 + d];
      den += sumP[pb];
    }
    attn0[((size_t)(b * 96 + l)) * 512 + e] = num / den;
  }
}

// ---------------------------------------------------------------------------
// trend_norm: moving_avg(k=25, edge-replicated) -> LayerNorm(seasonal) + trend
// ---------------------------------------------------------------------------
__global__ __launch_bounds__(256)
void trend_norm(const float* __restrict__ y, const float* __restrict__ g,
                const float* __restrict__ be, float* __restrict__ outp) {
  const int t = blockIdx.x, b = blockIdx.y;
  const int tid = threadIdx.x;
  __shared__ float red[256];
  __shared__ float red2[256];
  float seas[2], trend[2];
  float lsum = 0.f, lsum2 = 0.f;
#pragma unroll
  for (int u = 0; u < 2; ++u) {
    int d = tid + u * 256;
    float tr = 0.f;
    for (int j = -12; j <= 12; ++j) {
      int tt = t + j;
      tt = tt < 0 ? 0 : (tt > 95 ? 95 : tt);
      tr += y[((size_t)(b * 96 + tt)) * 512 + d];
    }
    tr *= (1.f / 25.f);
    float x = y[((size_t)(b * 96 + t)) * 512 + d];
    float se = x - tr;
    seas[u] = se;
    trend[u] = tr;
    lsum += se;
    lsum2 += se * se;
  }
  red[tid] = lsum;
  red2[tid] = lsum2;
  __syncthreads();
  for (int off = 128; off > 0; off >>= 1) {
    if (tid < off) {
      red[tid] += red[tid + off];
      red2[tid] += red2[tid + off];
    }
    __syncthreads();
  }
  float mu = red[0] / 512.f;
  float var = red2[0] / 512.f - mu * mu;
  float rs = rsqrtf(var + 1e-5f);
#pragma unroll
  for (int u = 0; u < 2; ++u) {
    int d = tid + u * 256;
    outp[((size_t)(b * 96 + t)) * 512 + d] = (seas[u] - mu) * rs * g[d] + be[d] + trend[u];
  }
}

// ---------------------------------------------------------------------------
// Penalty: sum(diff(om, axis=seq)^2) and sum(th^2) over a fused proj buffer.
// ---------------------------------------------------------------------------
__global__ __launch_bounds__(256)
void penalty(const float* __restrict__ base, int R, int nb, float mult,
             float* __restrict__ pen) {
  const int tid = threadIdx.x;
  size_t gid = (size_t)blockIdx.x * 256 + tid;
  size_t total = (size_t)nb * R * 16;
  float omv = 0.f, thv = 0.f;
  if (gid < total) {
    int j = (int)(gid & 15);
    size_t row = gid >> 4;
    int s = (int)(row % R);
    const float* r0 = base + row * NF;
    float th = r0[528 + j];
    thv = th * th;
    if (s < R - 1) {
      float d = r0[NF + 512 + j] - r0[512 + j];
      omv = d * d;
    }
  }
  __shared__ float ro[256], rt[256];
  ro[tid] = omv;
  rt[tid] = thv;
  __syncthreads();
  for (int off = 128; off > 0; off >>= 1) {
    if (tid < off) {
      ro[tid] += ro[tid + off];
      rt[tid] += rt[tid + off];
    }
    __syncthreads();
  }
  if (tid == 0) {
    atomicAdd(pen + 0, mult * ro[0]);
    atomicAdd(pen + 1, mult * rt[0]);
  }
}

// ---------------------------------------------------------------------------
// Layer-1 attention, MFMA. K,V staged in LDS with contiguous uint4 copies;
// Q direct; output via LDS transpose (aliased onto dead Ks). (R5 version —
// this fix took attn1 out of the top-5.) grid (48 lt, 8h, 8b).
// ---------------------------------------------------------------------------
__global__ __launch_bounds__(256)
void attn1_mfma(const ushort* __restrict__ Qr1, const ushort* __restrict__ Kr1b,
                const ushort* __restrict__ Vt1, ushort* __restrict__ attn1) {
  const int nwg = gridDim.x * gridDim.y * gridDim.z;
  const int flat = (blockIdx.z * gridDim.y + blockIdx.y) * gridDim.x + blockIdx.x;
  const int nf = xcd_swizzle(flat, nwg);
  const int lt = nf % gridDim.x;
  const int rest = nf / gridDim.x;
  const int h = rest % gridDim.y, b = rest / gridDim.y;
  const int l0 = lt * 64;
  const int tid = threadIdx.x;
  const int wv = tid >> 6, lane = tid & 63, quad = lane >> 4, col = lane & 15;

  __shared__ __align__(16) ushort Ks[96][136];  // 26.1 KB
  __shared__ __align__(16) ushort Vs[64][104];  // 13.3 KB
  __shared__ __align__(16) ushort Ps[64][104];  // 13.3 KB  (total 52.7 KB)
  ushort(*Os)[72] = reinterpret_cast<ushort(*)[72]>(&Ks[0][0]);

  const ushort* Qg = Qr1 + ((size_t)(b * 8 + h) * L_ + l0) * 128;
  const ushort* Kg = Kr1b + (size_t)(b * 8 + h) * 96 * 128;
  const ushort* Vg = Vt1 + (size_t)(b * 8 + h) * 64 * 96;

  for (int idx = tid; idx < 96 * 16; idx += 256) {
    int r = idx >> 4, c8 = (idx & 15) * 8;
    *(uint4*)&Ks[r][c8] = *(const uint4*)(Kg + (size_t)r * 128 + c8);
  }
  for (int idx = tid; idx < 64 * 12; idx += 256) {
    int r = idx / 12, c8 = (idx % 12) * 8;
    *(uint4*)&Vs[r][c8] = *(const uint4*)(Vg + (size_t)r * 96 + c8);
  }
  bf16x8 aq[4];
#pragma unroll
  for (int k = 0; k < 4; ++k)
    aq[k] = *(const bf16x8*)(Qg + ((size_t)(wv * 16 + col)) * 128 + k * 32 + quad * 8);
  __syncthreads();

  f32x4 sacc[6];
#pragma unroll
  for (int nt = 0; nt < 6; ++nt) {
    f32x4 z = {0.f, 0.f, 0.f, 0.f};
    sacc[nt] = z;
#pragma unroll
    for (int k = 0; k < 4; ++k) {
      bf16x8 bkf = *(const bf16x8*)&Ks[nt * 16 + col][k * 32 + quad * 8];
      sacc[nt] = mfma16(aq[k], bkf, sacc[nt]);
    }
  }
  float rsum[4] = {0.f, 0.f, 0.f, 0.f};
#pragma unroll
  for (int nt = 0; nt < 6; ++nt) {
#pragma unroll
    for (int r = 0; r < 4; ++r) {
      float p = __expf(sacc[nt][r] * 0.0625f);
      Ps[wv * 16 + quad * 4 + r][nt * 16 + col] = f2bf(p);
      rsum[r] += p;
    }
  }
#pragma unroll
  for (int r = 0; r < 4; ++r) {
#pragma unroll
    for (int off = 1; off < 16; off <<= 1) rsum[r] += __shfl_xor(rsum[r], off);
  }
  __syncthreads();  // Ps complete (implies all Ks reads done -> Os safe)
  bf16x8 ap[3];
#pragma unroll
  for (int kt = 0; kt < 3; ++kt)
    ap[kt] = *(const bf16x8*)&Ps[wv * 16 + col][kt * 32 + quad * 8];
  f32x4 oacc[4];
#pragma unroll
  for (int nt = 0; nt < 4; ++nt) {
    f32x4 z = {0.f, 0.f, 0.f, 0.f};
    oacc[nt] = z;
#pragma unroll
    for (int kt = 0; kt < 3; ++kt) {
      bf16x8 bvf = *(const bf16x8*)&Vs[nt * 16 + col][kt * 32 + quad * 8];
      oacc[nt] = mfma16(ap[kt], bvf, oacc[nt]);
    }
  }
  float inv[4];
#pragma unroll
  for (int r = 0; r < 4; ++r) inv[r] = 1.f / rsum[r];
#pragma unroll
  for (int nt = 0; nt < 4; ++nt) {
#pragma unroll
    for (int r = 0; r < 4; ++r) {
      Os[wv * 16 + quad * 4 + r][nt * 16 + col] = f2bf(oacc[nt][r] * inv[r]);
    }
  }
  __syncthreads();
  for (int idx = tid; idx < 64 * 8; idx += 256) {
    int l = idx >> 3, c8 = (idx & 7) * 8;
    *(uint4*)(attn1 + (size_t)(b * L_ + l0 + l) * 512 + h * 64 + c8) =
        *(const uint4*)&Os[l][c8];
  }
}

// ---------------------------------------------------------------------------
extern "C" void kernel_launch(void* const* d_in, const int* in_sizes, int n_in,
                              void* d_out, int out_size, void* d_ws, size_t ws_size,
                              hipStream_t stream) {
  (void)in_sizes; (void)n_in; (void)out_size; (void)ws_size;
  const float* queries = (const float*)d_in[0];
  const float* keys = (const float*)d_in[1];
  const float* values = (const float*)d_in[2];
  const float* Wq = (const float*)d_in[3];
  const float* bq = (const float*)d_in[4];
  const float* Wk = (const float*)d_in[5];
  const float* bk = (const float*)d_in[6];
  const float* Wv = (const float*)d_in[7];
  const float* bv = (const float*)d_in[8];
  const float* Wqo = (const float*)d_in[9];
  const float* bqo = (const float*)d_in[10];
  const float* Wko = (const float*)d_in[11];
  const float* bko = (const float*)d_in[12];
  const float* Wqt = (const float*)d_in[13];
  const float* bqt = (const float*)d_in[14];
  const float* Wkt = (const float*)d_in[15];
  const float* bkt = (const float*)d_in[16];
  const float* Wo = (const float*)d_in[17];
  const float* bo = (const float*)d_in[18];
  const float* I = (const float*)d_in[19];
  const float* ln_g = (const float*)d_in[20];
  const float* ln_b = (const float*)d_in[21];
  float* out = (float*)d_out;

  float* ws = (float*)d_ws;
  size_t off = 0;
  auto alloc = [&](size_t n) {
    float* p = ws + off;
    off += (n + 3) & ~(size_t)3;
    return p;
  };
  auto allocU = [&](size_t n) { return (ushort*)alloc((n + 1) / 2); };

  // fp32 packed weights (small-M gemms)
  float* WCAT0Q = alloc(512 * 544);
  float* WCAT1K = alloc(512 * 544);
  float* BCAT0Q = alloc(544);
  float* BCAT1K = alloc(544);
  // bf16 transposed weights (big gemms)
  ushort* BT0K = allocU(640 * 512);
  ushort* BT1Q = allocU(640 * 512);
  ushort* BTV0 = allocU(512 * 512);
  ushort* BTO1 = allocU(512 * 512);
  float* B0K = alloc(544);
  float* B1Q = alloc(544);
  float* BV0 = alloc(512);
  float* BO1 = alloc(512);
  float* pen = alloc(16);
  float* QF0 = alloc(96 * 544);
  ushort* Qr0bf = allocU(8 * 96 * 128);
  float* KF0 = alloc((size_t)24576 * 544);  // reused as QF1
  float* V0 = alloc((size_t)24576 * 512);   // bf16 V0 in first half; reused as Qr1
  float* attn0 = alloc(768 * 512);
  float* y0 = alloc(768 * 512);
  float* xind = alloc(768 * 512);
  float* KF1 = alloc(768 * 544);
  float* V1 = alloc(768 * 512);
  ushort* Kr1b = allocU((size_t)64 * 96 * 128);  // bf16 rotated K, layer 1
  ushort* Vt1 = allocU((size_t)64 * 64 * 96);    // bf16 transposed V, layer 1
  float* accP = alloc((size_t)64 * NSC * 96 * 64);
  float* sumP = alloc((size_t)64 * NSC * 96);
  // XB1/XB2 MUST stay adjacent: their union (2 x 12,582,912 ushorts) is
  // reused as Kr0 bf16 [64][3072][128] = 25,165,824 ushorts during attn0.
  ushort* XB1 = allocU((size_t)24576 * 512);  // keysB, then Kr0 lo, then queriesB
  ushort* XB2 = allocU((size_t)24576 * 512);  // valuesB, then Kr0 hi, then attn1 out
  ushort* Kr0U = XB1;
  ushort* Vt0U = allocU((size_t)64 * 64 * S_);  // 25.2 MB
  float* QF1 = KF0;
  ushort* V0b = (ushort*)V0;   // bf16 V0 [24576][512] (25 MB in the 50 MB region)
  ushort* Qr1U = (ushort*)V0;  // later: Qr1 bf16 (V0b dead after build_vt0)

  init_pen<<<1, 64, 0, stream>>>(pen);
  const int packBlocks = (512 * 544 + 255) / 256;
  pack_w<<<packBlocks, 256, 0, stream>>>(Wq, Wqo, Wqt, bq, bqo, bqt, WCAT0Q, BCAT0Q);
  pack_w<<<packBlocks, 256, 0, stream>>>(Wk + 262144, Wko + 8192, Wkt + 8192,
                                         bk + 512, bko + 16, bkt + 16, WCAT1K, BCAT1K);
  pack_wt_fused<<<(640 * 512 + 255) / 256, 256, 0, stream>>>(
      Wk, Wko, Wkt, bk, bko, bkt, BT0K, B0K);
  pack_wt_fused<<<(640 * 512 + 255) / 256, 256, 0, stream>>>(
      Wq + 262144, Wqo + 8192, Wqt + 8192, bq + 512, bqo + 16, bqt + 16, BT1Q, B1Q);
  pack_wt_plain<<<(512 * 512 + 255) / 256, 256, 0, stream>>>(Wv, bv, BTV0, BV0);
  pack_wt_plain<<<(512 * 512 + 255) / 256, 256, 0, stream>>>(Wo + 262144, bo + 512,
                                                             BTO1, BO1);
  const int castBlocks = (24576 * 512 / 8 + 255) / 256;
  cast_bf16<<<castBlocks, 256, 0, stream>>>(keys, XB1, 24576 * 512 / 8);
  cast_bf16<<<castBlocks, 256, 0, stream>>>(values, XB2, 24576 * 512 / 8);

  // ---- layer 0 ----
  gemm_bf16_mfma<<<dim3(5, 192), 256, 0, stream>>>(XB1, BT0K, B0K, KF0, 544, 544, 1, 0);
  gemm_bf16_mfma<<<dim3(4, 192), 256, 0, stream>>>(XB2, BTV0, BV0, V0b, 512, 512, 0, 1);
  gemm_k512<<<dim3(9, 2), 256, 0, stream>>>(I, WCAT0Q, BCAT0Q, QF0, 96, 544, 1);
  build_qr0<<<96, 256, 0, stream>>>(QF0, Qr0bf);
  penalty<<<(96 * 16 + 255) / 256, 256, 0, stream>>>(QF0, 96, 1, 8.f, pen);
  penalty<<<(24576 * 16 + 255) / 256, 256, 0, stream>>>(KF0, 3072, 8, 1.f, pen);
  build_kr0<<<24576, 256, 0, stream>>>(KF0, Kr0U);        // overwrites XB1+XB2
  build_vt0<<<dim3(48, 8, 8), 256, 0, stream>>>(V0b, Vt0U);
  attn0_mfma<<<dim3(8, 8, 8), 256, 0, stream>>>(Kr0U, Vt0U, Qr0bf, accP, sumP);
  attn0_stage2<<<dim3(96, 8), 256, 0, stream>>>(accP, sumP, attn0);
  gemm_k512<<<dim3(8, 12), 256, 0, stream>>>(attn0, Wo, bo, y0, 768, 512, 0);
  trend_norm<<<dim3(96, 8), 256, 0, stream>>>(y0, ln_g, ln_b, xind);

  // ---- layer 1 ----
  gemm_k512<<<dim3(9, 12), 256, 0, stream>>>(xind, WCAT1K, BCAT1K, KF1, 768, 544, 1);
  gemm_k512<<<dim3(8, 12), 256, 0, stream>>>(xind, Wv + 262144, bv + 512, V1, 768, 512, 0);
  build_kr1<<<768, 256, 0, stream>>>(KF1, Kr1b);
  build_vt1<<<dim3(8, 8), 256, 0, stream>>>(V1, Vt1);
  penalty<<<(768 * 16 + 255) / 256, 256, 0, stream>>>(KF1, 96, 8, 1.f, pen);
  cast_bf16<<<castBlocks, 256, 0, stream>>>(queries, XB1, 24576 * 512 / 8);
  gemm_bf16_mfma<<<dim3(5, 192), 256, 0, stream>>>(XB1, BT1Q, B1Q, QF1, 544, 544, 1, 0);
  penalty<<<(24576 * 16 + 255) / 256, 256, 0, stream>>>(QF1, 3072, 8, 1.f, pen);
  build_qr1<<<24576, 256, 0, stream>>>(QF1, Qr1U);        // overwrites V0b
  attn1_mfma<<<dim3(48, 8, 8), 256, 0, stream>>>(Qr1U, Kr1b, Vt1, XB2);
  gemm_bf16_mfma<<<dim3(4, 192), 256, 0, stream>>>(XB2, BTO1, BO1, out, 512, 512, 0, 0);
  write_pen<<<1, 64, 0, stream>>>(pen, out);
}